// Round 19
// baseline (236.516 us; speedup 1.0000x reference)
//
#include <hip/hip_runtime.h>
#include <hip/hip_bf16.h>

#define B_ 4
#define T_ 1024
#define D_ 256
#define H_ 8
#define WIN_ 64
#define CIN_ 128
#define DH_ 32
#define DFF_ 512
#define L_ 4
#define PSTR 152 // attn Ps/Vt LDS row stride (shorts)
#define FSTR 520 // ffn F-tile LDS row stride (shorts)
#define HSTR 264 // h1 bf16 LDS row stride (shorts)
#define WSTR 72  // BK=64 weight/A tile row stride (shorts)

typedef __attribute__((ext_vector_type(4))) short s16x4;
typedef __attribute__((ext_vector_type(8))) short s16x8;
typedef __attribute__((ext_vector_type(4))) float f32x4;

__device__ inline short f2bf(float f) {
    __hip_bfloat16 h = __float2bfloat16(f);
    return *reinterpret_cast<short*>(&h);
}

// ---------------- one-time weight prep
__global__ __launch_bounds__(256) void prep_w(
    const float* __restrict__ wqkv, const float* __restrict__ wo,
    const float* __restrict__ w1, const float* __restrict__ w2,
    const float* __restrict__ pw0, const float* __restrict__ pw1,
    const float* __restrict__ qw0, const float* __restrict__ qw1,
    short* __restrict__ dst) {
    const int N0 = 786432, N1 = 1048576, N2 = 1572864, NT = 2097152;
    const int NTOT = 2686976;
    for (int i = blockIdx.x * 256 + threadIdx.x; i < NTOT; i += gridDim.x * 256) {
        float v;
        if (i < NT) {
            if (i < N0) v = wqkv[i];
            else if (i < N1) v = wo[i - N0];
            else if (i < N2) v = w1[i - N1];
            else v = w2[i - N2];
        } else {
            int j = i - NT;
            const float* src;
            int I;
            if (j < 98304)       { src = pw0; I = 128; }
            else if (j < 294912) { src = pw1; I = 256; j -= 98304; }
            else if (j < 491520) { src = qw0; I = 256; j -= 294912; }
            else                 { src = qw1; I = 256; j -= 491520; }
            int o = j / (3 * I);
            int rem = j - o * 3 * I;
            int k = rem / I, ii = rem - k * I;
            v = src[(size_t)(o * I + ii) * 3 + k];
        }
        dst[i] = f2bf(v);
    }
}

// ---------------- fused im2col + conv-GEMM + LN2d-partial, 16x64 tile, BK=64,
// register-prefetched (T14). LNIN=1: apply LN2d(lnw,lnb from part_in)+ReLU to
// the input during staging (bit-identical to the former separate ln2d_apply).
template <int I_, int BTD, int LNIN>
__global__ __launch_bounds__(256) void gemm_conv16(
    const float* __restrict__ x, const short* __restrict__ Wr,
    const float* __restrict__ bias, float* __restrict__ Y, int O,
    float* __restrict__ part_out,
    const float* __restrict__ lnw, const float* __restrict__ lnb,
    const float* __restrict__ part_in) {
    const int K = 3 * I_;
    __shared__ short Al[16 * WSTR];
    __shared__ short Wl[64 * WSTR];
    __shared__ float sh[8];
    __shared__ float sstat[2];
    int tid = threadIdx.x;
    int col0 = blockIdx.x * 64;
    int row0 = blockIdx.y * 16;
    int b = row0 >> 10, t0 = row0 & 1023;
    int wave = tid >> 6, lane = tid & 63;
    int lg = lane >> 4, lr = lane & 15;
    f32x4 acc = {0.f, 0.f, 0.f, 0.f};

    if (LNIN && tid < 64) {
        float s = 0.f, ss = 0.f;
        const float2* p2 = (const float2*)part_in + (size_t)b * 256;
        for (int i = tid; i < 256; i += 64) { float2 v = p2[i]; s += v.x; ss += v.y; }
#pragma unroll
        for (int off = 32; off; off >>= 1) {
            s += __shfl_xor(s, off);
            ss += __shfl_xor(ss, off);
        }
        if (tid == 0) {
            float mu = s / (float)(I_ * T_);
            sstat[0] = mu;
            sstat[1] = rsqrtf(ss / (float)(I_ * T_) - mu * mu + 1e-5f);
        }
    }

    float areg[4], lreg[4], breg[4];

    // prologue: chunk 0
    {
        int k = 0, i0 = 0;
#pragma unroll
        for (int p = 0; p < 4; ++p) {
            int e = p * 256 + tid;
            int rr, cc;
            if (BTD) { rr = e >> 6; cc = e & 63; }
            else     { cc = e >> 4; rr = e & 15; }
            int tg = t0 + rr - 1 + k;
            bool ok = (tg >= 0 && tg < T_);
            areg[p] = ok ? (BTD ? x[((size_t)(b * T_ + tg)) * I_ + i0 + cc]
                                : x[((size_t)(b * I_ + i0 + cc)) * T_ + tg])
                         : 0.f;
            if (LNIN) {
                lreg[p] = ok ? lnw[(size_t)(i0 + cc) * T_ + tg] : 0.f;
                breg[p] = ok ? lnb[(size_t)(i0 + cc) * T_ + tg] : 0.f;
            }
        }
#pragma unroll
        for (int p = 0; p < 4; ++p) {
            int e = p * 256 + tid;
            int rr = e >> 4, c4 = (e & 15) * 4;
            // wreg handled below in loop; preload here
        }
    }
    s16x4 wreg[4];
#pragma unroll
    for (int p = 0; p < 4; ++p) {
        int e = p * 256 + tid;
        int rr = e >> 4, c4 = (e & 15) * 4;
        wreg[p] = *(const s16x4*)&Wr[(size_t)(col0 + rr) * K + c4];
    }
    __syncthreads();   // sstat ready (and no LDS written yet)
    float mu = LNIN ? sstat[0] : 0.f, rstd = LNIN ? sstat[1] : 0.f;

    for (int k0 = 0; k0 < K; k0 += 64) {
#pragma unroll
        for (int p = 0; p < 4; ++p) {
            int e = p * 256 + tid;
            int rr, cc;
            if (BTD) { rr = e >> 6; cc = e & 63; }
            else     { cc = e >> 4; rr = e & 15; }
            float v = areg[p];
            if (LNIN) v = fmaxf((v - mu) * rstd * lreg[p] + breg[p], 0.f) *
                          ((areg[p] == 0.f && lreg[p] == 0.f && breg[p] == 0.f) ? 0.f : 1.f);
            Al[rr * WSTR + cc] = f2bf(v);
        }
#pragma unroll
        for (int p = 0; p < 4; ++p) {
            int e = p * 256 + tid;
            int rr = e >> 4, c4 = (e & 15) * 4;
            *(s16x4*)&Wl[rr * WSTR + c4] = wreg[p];
        }
        __syncthreads();
        int kn = k0 + 64;
        if (kn < K) {
            int k = kn / I_;
            int i0 = kn - k * I_;
#pragma unroll
            for (int p = 0; p < 4; ++p) {
                int e = p * 256 + tid;
                int rr, cc;
                if (BTD) { rr = e >> 6; cc = e & 63; }
                else     { cc = e >> 4; rr = e & 15; }
                int tg = t0 + rr - 1 + k;
                bool ok = (tg >= 0 && tg < T_);
                areg[p] = ok ? (BTD ? x[((size_t)(b * T_ + tg)) * I_ + i0 + cc]
                                    : x[((size_t)(b * I_ + i0 + cc)) * T_ + tg])
                             : 0.f;
                if (LNIN) {
                    lreg[p] = ok ? lnw[(size_t)(i0 + cc) * T_ + tg] : 0.f;
                    breg[p] = ok ? lnb[(size_t)(i0 + cc) * T_ + tg] : 0.f;
                }
            }
#pragma unroll
            for (int p = 0; p < 4; ++p) {
                int e = p * 256 + tid;
                int rr = e >> 4, c4 = (e & 15) * 4;
                wreg[p] = *(const s16x4*)&Wr[(size_t)(col0 + rr) * K + kn + c4];
            }
        }
        s16x8 af0 = *(const s16x8*)&Al[lr * WSTR + lg * 8];
        s16x8 af1 = *(const s16x8*)&Al[lr * WSTR + 32 + lg * 8];
        s16x8 wf0 = *(const s16x8*)&Wl[(wave * 16 + lr) * WSTR + lg * 8];
        s16x8 wf1 = *(const s16x8*)&Wl[(wave * 16 + lr) * WSTR + 32 + lg * 8];
        acc = __builtin_amdgcn_mfma_f32_16x16x32_bf16(af0, wf0, acc, 0, 0, 0);
        acc = __builtin_amdgcn_mfma_f32_16x16x32_bf16(af1, wf1, acc, 0, 0, 0);
        __syncthreads();
    }

    int cg = col0 + wave * 16 + lr;
    float bv = bias[cg];
    float4 o;
    o.x = acc[0] + bv; o.y = acc[1] + bv; o.z = acc[2] + bv; o.w = acc[3] + bv;
    *(float4*)&Y[((size_t)(b * O + cg)) * 1024 + t0 + lg * 4] = o;

    float s = o.x + o.y + o.z + o.w;
    float ss = o.x * o.x + o.y * o.y + o.z * o.z + o.w * o.w;
#pragma unroll
    for (int off = 32; off; off >>= 1) {
        s += __shfl_xor(s, off);
        ss += __shfl_xor(ss, off);
    }
    if (lane == 0) { sh[wave * 2] = s; sh[wave * 2 + 1] = ss; }
    __syncthreads();
    if (tid == 0) {
        float ts = sh[0] + sh[2] + sh[4] + sh[6];
        float tss = sh[1] + sh[3] + sh[5] + sh[7];
        int slot = b * (gridDim.x * 64) + blockIdx.x * 64 + (blockIdx.y & 63);
        part_out[slot * 2] = ts;
        part_out[slot * 2 + 1] = tss;
    }
}

// ---------------- bf16-weight MFMA GEMM (QKV), 64x64 tile, BK=64, prefetched
template <int RELU, int BF16OUT>
__global__ __launch_bounds__(256) void gemm64w(
    const float* __restrict__ A, const short* __restrict__ Wbf,
    const float* __restrict__ bias, void* __restrict__ Yv,
    int M, int N, int K) {
    __shared__ short Al[64 * WSTR];
    __shared__ short Wl[64 * WSTR];
    int tid = threadIdx.x;
    int row0 = blockIdx.y * 64, col0 = blockIdx.x * 64;
    int wave = tid >> 6, lane = tid & 63;
    int wr = wave >> 1, wc = wave & 1;
    int lg = lane >> 4, lr = lane & 15;
    f32x4 acc[2][2] = {};

    float4 areg[4];
    s16x4 wreg[4];
#pragma unroll
    for (int p = 0; p < 4; ++p) {
        int e = p * 256 + tid;
        int rr = e >> 4, c4 = (e & 15) * 4;
        areg[p] = *(const float4*)&A[(size_t)(row0 + rr) * K + c4];
        wreg[p] = *(const s16x4*)&Wbf[(size_t)(col0 + rr) * K + c4];
    }

    for (int k0 = 0; k0 < K; k0 += 64) {
#pragma unroll
        for (int p = 0; p < 4; ++p) {
            int e = p * 256 + tid;
            int rr = e >> 4, c4 = (e & 15) * 4;
            s16x4 sa;
            sa[0] = f2bf(areg[p].x); sa[1] = f2bf(areg[p].y);
            sa[2] = f2bf(areg[p].z); sa[3] = f2bf(areg[p].w);
            *(s16x4*)&Al[rr * WSTR + c4] = sa;
            *(s16x4*)&Wl[rr * WSTR + c4] = wreg[p];
        }
        __syncthreads();
        int kn = k0 + 64;
        if (kn < K) {
#pragma unroll
            for (int p = 0; p < 4; ++p) {
                int e = p * 256 + tid;
                int rr = e >> 4, c4 = (e & 15) * 4;
                areg[p] = *(const float4*)&A[(size_t)(row0 + rr) * K + kn + c4];
                wreg[p] = *(const s16x4*)&Wbf[(size_t)(col0 + rr) * K + kn + c4];
            }
        }
#pragma unroll
        for (int s = 0; s < 2; ++s) {
            s16x8 af[2], wf[2];
#pragma unroll
            for (int i = 0; i < 2; ++i) {
                af[i] = *(const s16x8*)&Al[(wr * 32 + i * 16 + lr) * WSTR + s * 32 + lg * 8];
                wf[i] = *(const s16x8*)&Wl[(wc * 32 + i * 16 + lr) * WSTR + s * 32 + lg * 8];
            }
#pragma unroll
            for (int i = 0; i < 2; ++i)
#pragma unroll
                for (int j = 0; j < 2; ++j)
                    acc[i][j] = __builtin_amdgcn_mfma_f32_16x16x32_bf16(af[i], wf[j], acc[i][j], 0, 0, 0);
        }
        __syncthreads();
    }
#pragma unroll
    for (int i = 0; i < 2; ++i) {
        int rg = row0 + wr * 32 + i * 16 + lg * 4;
#pragma unroll
        for (int j = 0; j < 2; ++j) {
            int cg = col0 + wc * 32 + j * 16 + lr;
            float bv = bias[cg];
#pragma unroll
            for (int q = 0; q < 4; ++q) {
                float v = acc[i][j][q] + bv;
                if (RELU) v = fmaxf(v, 0.f);
                if (BF16OUT) ((short*)Yv)[(size_t)(rg + q) * N + cg] = f2bf(v);
                else ((float*)Yv)[(size_t)(rg + q) * N + cg] = v;
            }
        }
    }
}

// ---------------- fused layer tail, BK=64 + register prefetch (T14)
__global__ __launch_bounds__(512) void layer_tail(
    const short* __restrict__ ATTb, const short* __restrict__ Wobf,
    const float* __restrict__ bo, const short* __restrict__ W1bf,
    const float* __restrict__ b1, const short* __restrict__ W2bf,
    const float* __restrict__ b2, float* __restrict__ H,
    const float* __restrict__ ln1w, const float* __restrict__ ln1b,
    const float* __restrict__ ln2w, const float* __restrict__ ln2b) {
    __shared__ short As[16 * WSTR];
    __shared__ short Ws[256 * WSTR];
    __shared__ float Gf[16][260];
    __shared__ short h1b[16 * HSTR];
    __shared__ short Fs[16 * FSTR];
    __shared__ float G2[16][260];
    int tid = threadIdx.x;
    int wave = tid >> 6, lane = tid & 63;
    int lg = lane >> 4, lr = lane & 15;
    int m0 = blockIdx.x * 16;

    int wrow = tid >> 3, wc8 = (tid & 7) * 8;
    int arow = tid >> 4, ac4 = (tid & 15) * 4;

    s16x8 wreg[4];
    s16x4 areg;

    // ---- phase A: G1 = ATT @ Wo^T + bo
    f32x4 accA[2] = {};
    if (tid < 256)
        areg = *(const s16x4*)&ATTb[(size_t)(m0 + arow) * 256 + ac4];
#pragma unroll
    for (int u = 0; u < 4; ++u)
        wreg[u] = *(const s16x8*)&Wobf[(size_t)(wrow + u * 64) * 256 + wc8];
    for (int k0 = 0; k0 < 256; k0 += 64) {
        if (tid < 256) *(s16x4*)&As[arow * WSTR + ac4] = areg;
#pragma unroll
        for (int u = 0; u < 4; ++u)
            *(s16x8*)&Ws[(wrow + u * 64) * WSTR + wc8] = wreg[u];
        __syncthreads();
        int kn = k0 + 64;
        if (kn < 256) {
            if (tid < 256)
                areg = *(const s16x4*)&ATTb[(size_t)(m0 + arow) * 256 + kn + ac4];
#pragma unroll
            for (int u = 0; u < 4; ++u)
                wreg[u] = *(const s16x8*)&Wobf[(size_t)(wrow + u * 64) * 256 + kn + wc8];
        }
#pragma unroll
        for (int s = 0; s < 2; ++s) {
            s16x8 af = *(const s16x8*)&As[lr * WSTR + s * 32 + lg * 8];
#pragma unroll
            for (int j = 0; j < 2; ++j) {
                s16x8 wf = *(const s16x8*)&Ws[(wave * 32 + j * 16 + lr) * WSTR + s * 32 + lg * 8];
                accA[j] = __builtin_amdgcn_mfma_f32_16x16x32_bf16(af, wf, accA[j], 0, 0, 0);
            }
        }
        __syncthreads();
    }
#pragma unroll
    for (int j = 0; j < 2; ++j) {
        int col = wave * 32 + j * 16 + lr;
        float bv = bo[col];
#pragma unroll
        for (int q = 0; q < 4; ++q)
            Gf[lg * 4 + q][col] = accA[j][q] + bv;
    }
    __syncthreads();

    // ---- LN1
    for (int rr = 0; rr < 2; ++rr) {
        int row = wave * 2 + rr;
        size_t base = (size_t)(m0 + row) * D_;
        float x[4];
        float s = 0.f;
#pragma unroll
        for (int i = 0; i < 4; ++i) {
            int idx = i * 64 + lane;
            x[i] = H[base + idx] + Gf[row][idx];
            s += x[i];
        }
#pragma unroll
        for (int off = 32; off; off >>= 1) s += __shfl_xor(s, off);
        float mu = s * (1.f / D_);
        float ss = 0.f;
#pragma unroll
        for (int i = 0; i < 4; ++i) { float d = x[i] - mu; ss += d * d; }
#pragma unroll
        for (int off = 32; off; off >>= 1) ss += __shfl_xor(ss, off);
        float rstd = rsqrtf(ss * (1.f / D_) + 1e-5f);
#pragma unroll
        for (int i = 0; i < 4; ++i) {
            int idx = i * 64 + lane;
            float h1v = (x[i] - mu) * rstd * ln1w[idx] + ln1b[idx];
            Gf[row][idx] = h1v;
            h1b[row * HSTR + idx] = f2bf(h1v);
        }
    }
    __syncthreads();

    // ---- phase B: F = relu(h1 @ W1^T + b1)
    for (int nh = 0; nh < 2; ++nh) {
        const short* Wh = W1bf + (size_t)nh * 256 * 256;
        f32x4 acc1[2] = {};
#pragma unroll
        for (int u = 0; u < 4; ++u)
            wreg[u] = *(const s16x8*)&Wh[(size_t)(wrow + u * 64) * 256 + wc8];
        for (int k0 = 0; k0 < 256; k0 += 64) {
#pragma unroll
            for (int u = 0; u < 4; ++u)
                *(s16x8*)&Ws[(wrow + u * 64) * WSTR + wc8] = wreg[u];
            __syncthreads();
            int kn = k0 + 64;
            if (kn < 256) {
#pragma unroll
                for (int u = 0; u < 4; ++u)
                    wreg[u] = *(const s16x8*)&Wh[(size_t)(wrow + u * 64) * 256 + kn + wc8];
            }
#pragma unroll
            for (int s = 0; s < 2; ++s) {
                s16x8 af = *(const s16x8*)&h1b[lr * HSTR + k0 + s * 32 + lg * 8];
#pragma unroll
                for (int j = 0; j < 2; ++j) {
                    s16x8 wf = *(const s16x8*)&Ws[(wave * 32 + j * 16 + lr) * WSTR + s * 32 + lg * 8];
                    acc1[j] = __builtin_amdgcn_mfma_f32_16x16x32_bf16(af, wf, acc1[j], 0, 0, 0);
                }
            }
            __syncthreads();
        }
#pragma unroll
        for (int j = 0; j < 2; ++j) {
            int col = nh * 256 + wave * 32 + j * 16 + lr;
            float bv = b1[col];
#pragma unroll
            for (int q = 0; q < 4; ++q)
                Fs[(lg * 4 + q) * FSTR + col] = f2bf(fmaxf(acc1[j][q] + bv, 0.f));
        }
        __syncthreads();
    }

    // ---- phase C: G2 = F @ W2^T + b2
    f32x4 acc2[2] = {};
#pragma unroll
    for (int u = 0; u < 4; ++u)
        wreg[u] = *(const s16x8*)&W2bf[(size_t)(wrow + u * 64) * 512 + wc8];
    for (int k0 = 0; k0 < 512; k0 += 64) {
#pragma unroll
        for (int u = 0; u < 4; ++u)
            *(s16x8*)&Ws[(wrow + u * 64) * WSTR + wc8] = wreg[u];
        __syncthreads();
        int kn = k0 + 64;
        if (kn < 512) {
#pragma unroll
            for (int u = 0; u < 4; ++u)
                wreg[u] = *(const s16x8*)&W2bf[(size_t)(wrow + u * 64) * 512 + kn + wc8];
        }
#pragma unroll
        for (int s = 0; s < 2; ++s) {
            s16x8 af = *(const s16x8*)&Fs[lr * FSTR + k0 + s * 32 + lg * 8];
#pragma unroll
            for (int j = 0; j < 2; ++j) {
                s16x8 wf = *(const s16x8*)&Ws[(wave * 32 + j * 16 + lr) * WSTR + s * 32 + lg * 8];
                acc2[j] = __builtin_amdgcn_mfma_f32_16x16x32_bf16(af, wf, acc2[j], 0, 0, 0);
            }
        }
        __syncthreads();
    }
#pragma unroll
    for (int j = 0; j < 2; ++j) {
        int col = wave * 32 + j * 16 + lr;
        float bv = b2[col];
#pragma unroll
        for (int q = 0; q < 4; ++q)
            G2[lg * 4 + q][col] = acc2[j][q] + bv;
    }
    __syncthreads();

    // ---- LN2
    for (int rr = 0; rr < 2; ++rr) {
        int row = wave * 2 + rr;
        size_t base = (size_t)(m0 + row) * D_;
        float x[4];
        float s = 0.f;
#pragma unroll
        for (int i = 0; i < 4; ++i) {
            int idx = i * 64 + lane;
            x[i] = Gf[row][idx] + G2[row][idx];
            s += x[i];
        }
#pragma unroll
        for (int off = 32; off; off >>= 1) s += __shfl_xor(s, off);
        float mu = s * (1.f / D_);
        float ss = 0.f;
#pragma unroll
        for (int i = 0; i < 4; ++i) { float d = x[i] - mu; ss += d * d; }
#pragma unroll
        for (int off = 32; off; off >>= 1) ss += __shfl_xor(ss, off);
        float rstd = rsqrtf(ss * (1.f / D_) + 1e-5f);
#pragma unroll
        for (int i = 0; i < 4; ++i) {
            int idx = i * 64 + lane;
            H[base + idx] = (x[i] - mu) * rstd * ln2w[idx] + ln2b[idx];
        }
    }
}

// ---------------- MFMA banded attention (bf16 in, bf16 out)
__global__ __launch_bounds__(256) void attn_mfma(
    const short* __restrict__ qkv, short* __restrict__ out) {
    int q0 = blockIdx.x * 64;
    int h = blockIdx.y, b = blockIdx.z;
    int tid = threadIdx.x;
    int wave = tid >> 6, lane = tid & 63;
    int lg = lane >> 4;
    int lr = lane & 15;
    const int j0 = q0 - 64;

    __shared__ short Qs[64][40];
    __shared__ short Ks[128][40];
    __shared__ short Vt[32][PSTR];
    __shared__ short Ps[64][PSTR];

#pragma unroll
    for (int u = 0; u < 2; ++u) {
        int task = tid + 256 * u;
        int r = task >> 3, c = (task & 7) * 4;
        *(s16x4*)&Qs[r][c] =
            *(const s16x4*)&qkv[((size_t)(b * T_ + q0 + r)) * 768 + h * 32 + c];
    }
#pragma unroll
    for (int u = 0; u < 4; ++u) {
        int task = tid + 256 * u;
        int r = task >> 3, c = (task & 7) * 4;
        int jg = j0 + r;
        s16x4 sa = {0, 0, 0, 0};
        if (jg >= 0)
            sa = *(const s16x4*)&qkv[((size_t)(b * T_ + jg)) * 768 + 256 + h * 32 + c];
        *(s16x4*)&Ks[r][c] = sa;
    }
#pragma unroll
    for (int u = 0; u < 4; ++u) {
        int task = tid + 256 * u;
        int r = task >> 3, c = (task & 7) * 4;
        int jg = j0 + r;
        s16x4 v4 = {0, 0, 0, 0};
        if (jg >= 0)
            v4 = *(const s16x4*)&qkv[((size_t)(b * T_ + jg)) * 768 + 512 + h * 32 + c];
        Vt[c + 0][r] = v4[0];
        Vt[c + 1][r] = v4[1];
        Vt[c + 2][r] = v4[2];
        Vt[c + 3][r] = v4[3];
    }
    __syncthreads();

    s16x8 aq = *(const s16x8*)&Qs[16 * wave + lr][lg * 8];
    f32x4 sacc[8];
#pragma unroll
    for (int j = 0; j < 8; ++j) {
        s16x8 bk = *(const s16x8*)&Ks[16 * j + lr][lg * 8];
        f32x4 z = {0.f, 0.f, 0.f, 0.f};
        sacc[j] = __builtin_amdgcn_mfma_f32_16x16x32_bf16(aq, bk, z, 0, 0, 0);
    }

    const float scale = 0.17677669529663687f;
#pragma unroll
    for (int j = 0; j < 8; ++j) {
        int jg = j0 + 16 * j + lr;
#pragma unroll
        for (int q = 0; q < 4; ++q) {
            int qi = q0 + 16 * wave + lg * 4 + q;
            bool ok = ((jg >= qi - WIN_) && (jg < qi) && (jg >= 0)) || (qi == 0 && jg == 0);
            sacc[j][q] = ok ? sacc[j][q] * scale : -1e30f;
        }
    }
#pragma unroll
    for (int q = 0; q < 4; ++q) {
        float m = sacc[0][q];
#pragma unroll
        for (int j = 1; j < 8; ++j) m = fmaxf(m, sacc[j][q]);
#pragma unroll
        for (int off = 1; off < 16; off <<= 1) m = fmaxf(m, __shfl_xor(m, off));
        float e[8], sum = 0.f;
#pragma unroll
        for (int j = 0; j < 8; ++j) { e[j] = __expf(sacc[j][q] - m); sum += e[j]; }
#pragma unroll
        for (int off = 1; off < 16; off <<= 1) sum += __shfl_xor(sum, off);
        float inv = 1.f / sum;
        int row = 16 * wave + lg * 4 + q;
#pragma unroll
        for (int j = 0; j < 8; ++j) Ps[row][16 * j + lr] = f2bf(e[j] * inv);
    }

    f32x4 oacc[2] = {};
#pragma unroll
    for (int kk = 0; kk < 4; ++kk) {
        s16x8 ap = *(const s16x8*)&Ps[16 * wave + lr][kk * 32 + lg * 8];
#pragma unroll
        for (int n = 0; n < 2; ++n) {
            s16x8 bv = *(const s16x8*)&Vt[16 * n + lr][kk * 32 + lg * 8];
            oacc[n] = __builtin_amdgcn_mfma_f32_16x16x32_bf16(ap, bv, oacc[n], 0, 0, 0);
        }
    }
#pragma unroll
    for (int n = 0; n < 2; ++n)
#pragma unroll
        for (int q = 0; q < 4; ++q) {
            int qi = q0 + 16 * wave + lg * 4 + q;
            out[((size_t)(b * T_ + qi)) * D_ + h * 32 + 16 * n + lr] = f2bf(oacc[n][q]);
        }
}

// ---------------- LN2d apply + ReLU (float4); stats reduced from part2 in-kernel
__global__ __launch_bounds__(256) void ln2d_apply(
    const float* __restrict__ x, const float* __restrict__ w,
    const float* __restrict__ bb, const float* __restrict__ part2,
    float* __restrict__ y, int CT, int npart) {
    int b = blockIdx.y;
    int tid = threadIdx.x;
    __shared__ float sstat[2];
    if (tid < 64) {
        float s = 0.f, ss = 0.f;
        const float2* p2 = (const float2*)part2 + (size_t)b * npart;
        for (int i = tid; i < npart; i += 64) { float2 v = p2[i]; s += v.x; ss += v.y; }
#pragma unroll
        for (int off = 32; off; off >>= 1) {
            s += __shfl_xor(s, off);
            ss += __shfl_xor(ss, off);
        }
        if (tid == 0) {
            float mu = s / (float)CT;
            sstat[0] = mu;
            sstat[1] = rsqrtf(ss / (float)CT - mu * mu + 1e-5f);
        }
    }
    __syncthreads();
    float mu = sstat[0], rstd = sstat[1];
    int idx = blockIdx.x * 256 + tid;
    const float4* x4 = (const float4*)(x + (size_t)b * CT);
    const float4* w4 = (const float4*)w;
    const float4* b4 = (const float4*)bb;
    float4* y4 = (float4*)(y + (size_t)b * CT);
    float4 v = x4[idx], wv = w4[idx], bv = b4[idx];
    float4 r;
    r.x = fmaxf((v.x - mu) * rstd * wv.x + bv.x, 0.f);
    r.y = fmaxf((v.y - mu) * rstd * wv.y + bv.y, 0.f);
    r.z = fmaxf((v.z - mu) * rstd * wv.z + bv.z, 0.f);
    r.w = fmaxf((v.w - mu) * rstd * wv.w + bv.w, 0.f);
    y4[idx] = r;
}

// ---------------- LN2d apply + ReLU + transpose + pos add: [B,D,T] -> [B,T,D]
__global__ __launch_bounds__(256) void ln2d_apply_t(
    const float* __restrict__ x, const float* __restrict__ w,
    const float* __restrict__ bb, const float* __restrict__ part2,
    const float* __restrict__ pos, float* __restrict__ h, int npart) {
    int t0 = blockIdx.x * 32;
    int d0 = blockIdx.y * 32;
    int b = blockIdx.z;
    int tid = threadIdx.x;
    __shared__ float sstat[2];
    if (tid < 64) {
        float s = 0.f, ss = 0.f;
        const float2* p2 = (const float2*)part2 + (size_t)b * npart;
        for (int i = tid; i < npart; i += 64) { float2 v = p2[i]; s += v.x; ss += v.y; }
#pragma unroll
        for (int off = 32; off; off >>= 1) {
            s += __shfl_xor(s, off);
            ss += __shfl_xor(ss, off);
        }
        if (tid == 0) {
            float mu = s / (float)(D_ * T_);
            sstat[0] = mu;
            sstat[1] = rsqrtf(ss / (float)(D_ * T_) - mu * mu + 1e-5f);
        }
    }
    __syncthreads();
    float mu = sstat[0], rstd = sstat[1];
    __shared__ float xs[32][33];
    int tt = tid & 31, dd = tid >> 5;
#pragma unroll
    for (int p = 0; p < 4; ++p) {
        int d = d0 + dd + p * 8;
        size_t off = ((size_t)b * D_ + d) * T_ + t0 + tt;
        size_t woff = (size_t)d * T_ + t0 + tt;
        float v = (x[off] - mu) * rstd * w[woff] + bb[woff];
        xs[dd + p * 8][tt] = fmaxf(v, 0.f);
    }
    __syncthreads();
    int dd2 = tid & 31, tt2 = tid >> 5;
#pragma unroll
    for (int p = 0; p < 4; ++p) {
        int t = t0 + tt2 + p * 8;
        h[((size_t)(b * T_ + t)) * D_ + d0 + dd2] =
            xs[dd2][tt2 + p * 8] + pos[(size_t)t * D_ + d0 + dd2];
    }
}

extern "C" void kernel_launch(void* const* d_in, const int* in_sizes, int n_in,
                              void* d_out, int out_size, void* d_ws, size_t ws_size,
                              hipStream_t stream) {
    const float* x        = (const float*)d_in[0];
    const float* pre_w0   = (const float*)d_in[1];
    const float* pre_b0   = (const float*)d_in[2];
    const float* pre_lnw0 = (const float*)d_in[3];
    const float* pre_lnb0 = (const float*)d_in[4];
    const float* pre_w1   = (const float*)d_in[5];
    const float* pre_b1   = (const float*)d_in[6];
    const float* pre_lnw1 = (const float*)d_in[7];
    const float* pre_lnb1 = (const float*)d_in[8];
    const float* pos_emb  = (const float*)d_in[9];
    const float* Wqkv     = (const float*)d_in[10];
    const float* bqkv     = (const float*)d_in[11];
    const float* Wo       = (const float*)d_in[12];
    const float* bo       = (const float*)d_in[13];
    const float* ln1w     = (const float*)d_in[14];
    const float* ln1b     = (const float*)d_in[15];
    const float* W1       = (const float*)d_in[16];
    const float* b1       = (const float*)d_in[17];
    const float* W2       = (const float*)d_in[18];
    const float* b2       = (const float*)d_in[19];
    const float* ln2w     = (const float*)d_in[20];
    const float* ln2b     = (const float*)d_in[21];
    const float* post_w0  = (const float*)d_in[22];
    const float* post_b0  = (const float*)d_in[23];
    const float* post_lnw0= (const float*)d_in[24];
    const float* post_lnb0= (const float*)d_in[25];
    const float* post_w1  = (const float*)d_in[26];
    const float* post_b1  = (const float*)d_in[27];
    const float* post_lnw1= (const float*)d_in[28];
    const float* post_lnb1= (const float*)d_in[29];

    float* ws = (float*)d_ws;
    const size_t M1 = 1u << 20;              // 1M floats
    float* H     = ws;                       // [B,T,D] fp32
    float* A0    = ws + 1 * M1;              // [B,D,T] fp32 (pre/post only)
    float* A1    = ws + 2 * M1;              // [B,D,T] fp32 (pre/post only)
    short* QKVb  = (short*)(ws + 1 * M1);    // [B,T,768] bf16 (aliases A0/A1)
    short* ATTb  = (short*)(ws + 5 * M1);    // [B,T,256] bf16
    short* wbf   = (short*)(ws + 6 * M1);    // transformer weights bf16
    short* wqkv_bf = wbf;
    short* wo_bf   = wbf + 786432;
    short* w1_bf   = wbf + 1048576;
    short* w2_bf   = wbf + 1572864;
    short* cwbf  = wbf + 2097152;            // conv weights reordered
    short* cw_pre0  = cwbf;                  // [256][3*128]
    short* cw_pre1  = cwbf + 98304;          // [256][3*256]
    short* cw_post0 = cwbf + 294912;         // [256][3*256]
    short* cw_post1 = cwbf + 491520;         // [128][3*256]
    float* part2a = ws + 8 * M1;             // 2048 floats
    float* part2b = part2a + 2048;           // 2048 floats

    const int M = B_ * T_;  // 4096

    // ---- one-time weight prep
    prep_w<<<2048, 256, 0, stream>>>(Wqkv, Wo, W1, W2,
                                     pre_w0, pre_w1, post_w0, post_w1, wbf);

    // ---- pre stage: conv0 -> conv1(LN inline) -> apply_t
    gemm_conv16<128, 0, 0><<<dim3(D_ / 64, M / 16), 256, 0, stream>>>(
        x, cw_pre0, pre_b0, A0, D_, part2a, nullptr, nullptr, nullptr);
    gemm_conv16<256, 0, 1><<<dim3(D_ / 64, M / 16), 256, 0, stream>>>(
        A0, cw_pre1, pre_b1, A1, D_, part2b, pre_lnw0, pre_lnb0, part2a);
    ln2d_apply_t<<<dim3(T_ / 32, D_ / 32, B_), 256, 0, stream>>>(
        A1, pre_lnw1, pre_lnb1, part2b, pos_emb, H, 256);

    // ---- transformer layers (3 dispatches each)
    for (int l = 0; l < L_; ++l) {
        gemm64w<0, 1><<<dim3(768 / 64, M / 64), 256, 0, stream>>>(
            H, wqkv_bf + (size_t)l * 196608, bqkv + (size_t)l * 768, QKVb, M, 768, D_);
        attn_mfma<<<dim3(T_ / 64, H_, B_), 256, 0, stream>>>(QKVb, ATTb);
        layer_tail<<<M / 16, 512, 0, stream>>>(
            ATTb, wo_bf + (size_t)l * 65536, bo + (size_t)l * D_,
            w1_bf + (size_t)l * 131072, b1 + (size_t)l * DFF_,
            w2_bf + (size_t)l * 131072, b2 + (size_t)l * D_, H,
            ln1w + (size_t)l * D_, ln1b + (size_t)l * D_,
            ln2w + (size_t)l * D_, ln2b + (size_t)l * D_);
    }

    // ---- post stage: conv0 -> conv1(LN inline) -> final apply
    gemm_conv16<256, 1, 0><<<dim3(D_ / 64, M / 16), 256, 0, stream>>>(
        H, cw_post0, post_b0, A1, D_, part2a, nullptr, nullptr, nullptr);
    gemm_conv16<256, 0, 1><<<dim3(CIN_ / 64, M / 16), 256, 0, stream>>>(
        A1, cw_post1, post_b1, A0, CIN_, part2b, post_lnw0, post_lnb0, part2a);
    ln2d_apply<<<dim3(CIN_ * T_ / 1024, B_), 256, 0, stream>>>(
        A0, post_lnw1, post_lnb1, part2b, (float*)d_out, CIN_ * T_, 128);
}

// Round 20
// 222.201 us; speedup vs baseline: 1.0644x; 1.0644x over previous
//
#include <hip/hip_runtime.h>
#include <hip/hip_bf16.h>

#define B_ 4
#define T_ 1024
#define D_ 256
#define H_ 8
#define WIN_ 64
#define CIN_ 128
#define DH_ 32
#define DFF_ 512
#define L_ 4
#define PSTR 152 // attn Ps/Vt LDS row stride (shorts)
#define FSTR 520 // ffn F-tile LDS row stride (shorts)
#define HSTR 264 // h1 bf16 LDS row stride (shorts)
#define WSTR 72  // BK=64 weight/A tile row stride (shorts)

typedef __attribute__((ext_vector_type(4))) short s16x4;
typedef __attribute__((ext_vector_type(8))) short s16x8;
typedef __attribute__((ext_vector_type(4))) float f32x4;

__device__ inline short f2bf(float f) {
    __hip_bfloat16 h = __float2bfloat16(f);
    return *reinterpret_cast<short*>(&h);
}

// ---------------- one-time weight prep
__global__ __launch_bounds__(256) void prep_w(
    const float* __restrict__ wqkv, const float* __restrict__ wo,
    const float* __restrict__ w1, const float* __restrict__ w2,
    const float* __restrict__ pw0, const float* __restrict__ pw1,
    const float* __restrict__ qw0, const float* __restrict__ qw1,
    short* __restrict__ dst) {
    const int N0 = 786432, N1 = 1048576, N2 = 1572864, NT = 2097152;
    const int NTOT = 2686976;
    for (int i = blockIdx.x * 256 + threadIdx.x; i < NTOT; i += gridDim.x * 256) {
        float v;
        if (i < NT) {
            if (i < N0) v = wqkv[i];
            else if (i < N1) v = wo[i - N0];
            else if (i < N2) v = w1[i - N1];
            else v = w2[i - N2];
        } else {
            int j = i - NT;
            const float* src;
            int I;
            if (j < 98304)       { src = pw0; I = 128; }
            else if (j < 294912) { src = pw1; I = 256; j -= 98304; }
            else if (j < 491520) { src = qw0; I = 256; j -= 294912; }
            else                 { src = qw1; I = 256; j -= 491520; }
            int o = j / (3 * I);
            int rem = j - o * 3 * I;
            int k = rem / I, ii = rem - k * I;
            v = src[(size_t)(o * I + ii) * 3 + k];
        }
        dst[i] = f2bf(v);
    }
}

// ---------------- fused im2col + conv-GEMM + LN2d-partial, 16x64 tile, BK=64,
// register-prefetched (T14)
template <int I_, int BTD>
__global__ __launch_bounds__(256) void gemm_conv16(
    const float* __restrict__ x, const short* __restrict__ Wr,
    const float* __restrict__ bias, float* __restrict__ Y, int O,
    float* __restrict__ part2) {
    const int K = 3 * I_;
    __shared__ short Al[16 * WSTR];
    __shared__ short Wl[64 * WSTR];
    __shared__ float sh[8];
    int tid = threadIdx.x;
    int col0 = blockIdx.x * 64;
    int row0 = blockIdx.y * 16;
    int b = row0 >> 10, t0 = row0 & 1023;
    int wave = tid >> 6, lane = tid & 63;
    int lg = lane >> 4, lr = lane & 15;
    f32x4 acc = {0.f, 0.f, 0.f, 0.f};

    float areg[4];
    s16x4 wreg[4];

    // prologue: chunk 0
    {
        int k = 0, i0 = 0;
#pragma unroll
        for (int p = 0; p < 4; ++p) {
            int e = p * 256 + tid;
            int rr, cc;
            if (BTD) { rr = e >> 6; cc = e & 63; }
            else     { cc = e >> 4; rr = e & 15; }
            int tg = t0 + rr - 1 + k;
            areg[p] = (tg >= 0 && tg < T_)
                          ? (BTD ? x[((size_t)(b * T_ + tg)) * I_ + i0 + cc]
                                 : x[((size_t)(b * I_ + i0 + cc)) * T_ + tg])
                          : 0.f;
        }
#pragma unroll
        for (int p = 0; p < 4; ++p) {
            int e = p * 256 + tid;
            int rr = e >> 4, c4 = (e & 15) * 4;
            wreg[p] = *(const s16x4*)&Wr[(size_t)(col0 + rr) * K + c4];
        }
    }

    for (int k0 = 0; k0 < K; k0 += 64) {
#pragma unroll
        for (int p = 0; p < 4; ++p) {
            int e = p * 256 + tid;
            int rr, cc;
            if (BTD) { rr = e >> 6; cc = e & 63; }
            else     { cc = e >> 4; rr = e & 15; }
            Al[rr * WSTR + cc] = f2bf(areg[p]);
        }
#pragma unroll
        for (int p = 0; p < 4; ++p) {
            int e = p * 256 + tid;
            int rr = e >> 4, c4 = (e & 15) * 4;
            *(s16x4*)&Wl[rr * WSTR + c4] = wreg[p];
        }
        __syncthreads();
        int kn = k0 + 64;
        if (kn < K) {
            int k = kn / I_;
            int i0 = kn - k * I_;
#pragma unroll
            for (int p = 0; p < 4; ++p) {
                int e = p * 256 + tid;
                int rr, cc;
                if (BTD) { rr = e >> 6; cc = e & 63; }
                else     { cc = e >> 4; rr = e & 15; }
                int tg = t0 + rr - 1 + k;
                areg[p] = (tg >= 0 && tg < T_)
                              ? (BTD ? x[((size_t)(b * T_ + tg)) * I_ + i0 + cc]
                                     : x[((size_t)(b * I_ + i0 + cc)) * T_ + tg])
                              : 0.f;
            }
#pragma unroll
            for (int p = 0; p < 4; ++p) {
                int e = p * 256 + tid;
                int rr = e >> 4, c4 = (e & 15) * 4;
                wreg[p] = *(const s16x4*)&Wr[(size_t)(col0 + rr) * K + kn + c4];
            }
        }
        s16x8 af0 = *(const s16x8*)&Al[lr * WSTR + lg * 8];
        s16x8 af1 = *(const s16x8*)&Al[lr * WSTR + 32 + lg * 8];
        s16x8 wf0 = *(const s16x8*)&Wl[(wave * 16 + lr) * WSTR + lg * 8];
        s16x8 wf1 = *(const s16x8*)&Wl[(wave * 16 + lr) * WSTR + 32 + lg * 8];
        acc = __builtin_amdgcn_mfma_f32_16x16x32_bf16(af0, wf0, acc, 0, 0, 0);
        acc = __builtin_amdgcn_mfma_f32_16x16x32_bf16(af1, wf1, acc, 0, 0, 0);
        __syncthreads();
    }

    int cg = col0 + wave * 16 + lr;
    float bv = bias[cg];
    float4 o;
    o.x = acc[0] + bv; o.y = acc[1] + bv; o.z = acc[2] + bv; o.w = acc[3] + bv;
    *(float4*)&Y[((size_t)(b * O + cg)) * 1024 + t0 + lg * 4] = o;

    float s = o.x + o.y + o.z + o.w;
    float ss = o.x * o.x + o.y * o.y + o.z * o.z + o.w * o.w;
#pragma unroll
    for (int off = 32; off; off >>= 1) {
        s += __shfl_xor(s, off);
        ss += __shfl_xor(ss, off);
    }
    if (lane == 0) { sh[wave * 2] = s; sh[wave * 2 + 1] = ss; }
    __syncthreads();
    if (tid == 0) {
        float ts = sh[0] + sh[2] + sh[4] + sh[6];
        float tss = sh[1] + sh[3] + sh[5] + sh[7];
        int slot = b * (gridDim.x * 64) + blockIdx.x * 64 + (blockIdx.y & 63);
        part2[slot * 2] = ts;
        part2[slot * 2 + 1] = tss;
    }
}

// ---------------- bf16-weight MFMA GEMM (QKV), 64x64 tile, BK=64, prefetched
template <int RELU, int BF16OUT>
__global__ __launch_bounds__(256) void gemm64w(
    const float* __restrict__ A, const short* __restrict__ Wbf,
    const float* __restrict__ bias, void* __restrict__ Yv,
    int M, int N, int K) {
    __shared__ short Al[64 * WSTR];
    __shared__ short Wl[64 * WSTR];
    int tid = threadIdx.x;
    int row0 = blockIdx.y * 64, col0 = blockIdx.x * 64;
    int wave = tid >> 6, lane = tid & 63;
    int wr = wave >> 1, wc = wave & 1;
    int lg = lane >> 4, lr = lane & 15;
    f32x4 acc[2][2] = {};

    float4 areg[4];
    s16x4 wreg[4];
#pragma unroll
    for (int p = 0; p < 4; ++p) {
        int e = p * 256 + tid;
        int rr = e >> 4, c4 = (e & 15) * 4;
        areg[p] = *(const float4*)&A[(size_t)(row0 + rr) * K + c4];
        wreg[p] = *(const s16x4*)&Wbf[(size_t)(col0 + rr) * K + c4];
    }

    for (int k0 = 0; k0 < K; k0 += 64) {
#pragma unroll
        for (int p = 0; p < 4; ++p) {
            int e = p * 256 + tid;
            int rr = e >> 4, c4 = (e & 15) * 4;
            s16x4 sa;
            sa[0] = f2bf(areg[p].x); sa[1] = f2bf(areg[p].y);
            sa[2] = f2bf(areg[p].z); sa[3] = f2bf(areg[p].w);
            *(s16x4*)&Al[rr * WSTR + c4] = sa;
            *(s16x4*)&Wl[rr * WSTR + c4] = wreg[p];
        }
        __syncthreads();
        int kn = k0 + 64;
        if (kn < K) {
#pragma unroll
            for (int p = 0; p < 4; ++p) {
                int e = p * 256 + tid;
                int rr = e >> 4, c4 = (e & 15) * 4;
                areg[p] = *(const float4*)&A[(size_t)(row0 + rr) * K + kn + c4];
                wreg[p] = *(const s16x4*)&Wbf[(size_t)(col0 + rr) * K + kn + c4];
            }
        }
#pragma unroll
        for (int s = 0; s < 2; ++s) {
            s16x8 af[2], wf[2];
#pragma unroll
            for (int i = 0; i < 2; ++i) {
                af[i] = *(const s16x8*)&Al[(wr * 32 + i * 16 + lr) * WSTR + s * 32 + lg * 8];
                wf[i] = *(const s16x8*)&Wl[(wc * 32 + i * 16 + lr) * WSTR + s * 32 + lg * 8];
            }
#pragma unroll
            for (int i = 0; i < 2; ++i)
#pragma unroll
                for (int j = 0; j < 2; ++j)
                    acc[i][j] = __builtin_amdgcn_mfma_f32_16x16x32_bf16(af[i], wf[j], acc[i][j], 0, 0, 0);
        }
        __syncthreads();
    }
#pragma unroll
    for (int i = 0; i < 2; ++i) {
        int rg = row0 + wr * 32 + i * 16 + lg * 4;
#pragma unroll
        for (int j = 0; j < 2; ++j) {
            int cg = col0 + wc * 32 + j * 16 + lr;
            float bv = bias[cg];
#pragma unroll
            for (int q = 0; q < 4; ++q) {
                float v = acc[i][j][q] + bv;
                if (RELU) v = fmaxf(v, 0.f);
                if (BF16OUT) ((short*)Yv)[(size_t)(rg + q) * N + cg] = f2bf(v);
                else ((float*)Yv)[(size_t)(rg + q) * N + cg] = v;
            }
        }
    }
}

// ---------------- fused layer tail, BK=64 + register prefetch (T14)
__global__ __launch_bounds__(512) void layer_tail(
    const short* __restrict__ ATTb, const short* __restrict__ Wobf,
    const float* __restrict__ bo, const short* __restrict__ W1bf,
    const float* __restrict__ b1, const short* __restrict__ W2bf,
    const float* __restrict__ b2, float* __restrict__ H,
    const float* __restrict__ ln1w, const float* __restrict__ ln1b,
    const float* __restrict__ ln2w, const float* __restrict__ ln2b) {
    __shared__ short As[16 * WSTR];
    __shared__ short Ws[256 * WSTR];
    __shared__ float Gf[16][260];
    __shared__ short h1b[16 * HSTR];
    __shared__ short Fs[16 * FSTR];
    __shared__ float G2[16][260];
    int tid = threadIdx.x;
    int wave = tid >> 6, lane = tid & 63;
    int lg = lane >> 4, lr = lane & 15;
    int m0 = blockIdx.x * 16;

    int wrow = tid >> 3, wc8 = (tid & 7) * 8;
    int arow = tid >> 4, ac4 = (tid & 15) * 4;

    s16x8 wreg[4];
    s16x4 areg;

    // ---- phase A: G1 = ATT @ Wo^T + bo
    f32x4 accA[2] = {};
    if (tid < 256)
        areg = *(const s16x4*)&ATTb[(size_t)(m0 + arow) * 256 + ac4];
#pragma unroll
    for (int u = 0; u < 4; ++u)
        wreg[u] = *(const s16x8*)&Wobf[(size_t)(wrow + u * 64) * 256 + wc8];
    for (int k0 = 0; k0 < 256; k0 += 64) {
        if (tid < 256) *(s16x4*)&As[arow * WSTR + ac4] = areg;
#pragma unroll
        for (int u = 0; u < 4; ++u)
            *(s16x8*)&Ws[(wrow + u * 64) * WSTR + wc8] = wreg[u];
        __syncthreads();
        int kn = k0 + 64;
        if (kn < 256) {
            if (tid < 256)
                areg = *(const s16x4*)&ATTb[(size_t)(m0 + arow) * 256 + kn + ac4];
#pragma unroll
            for (int u = 0; u < 4; ++u)
                wreg[u] = *(const s16x8*)&Wobf[(size_t)(wrow + u * 64) * 256 + kn + wc8];
        }
#pragma unroll
        for (int s = 0; s < 2; ++s) {
            s16x8 af = *(const s16x8*)&As[lr * WSTR + s * 32 + lg * 8];
#pragma unroll
            for (int j = 0; j < 2; ++j) {
                s16x8 wf = *(const s16x8*)&Ws[(wave * 32 + j * 16 + lr) * WSTR + s * 32 + lg * 8];
                accA[j] = __builtin_amdgcn_mfma_f32_16x16x32_bf16(af, wf, accA[j], 0, 0, 0);
            }
        }
        __syncthreads();
    }
#pragma unroll
    for (int j = 0; j < 2; ++j) {
        int col = wave * 32 + j * 16 + lr;
        float bv = bo[col];
#pragma unroll
        for (int q = 0; q < 4; ++q)
            Gf[lg * 4 + q][col] = accA[j][q] + bv;
    }
    __syncthreads();

    // ---- LN1
    for (int rr = 0; rr < 2; ++rr) {
        int row = wave * 2 + rr;
        size_t base = (size_t)(m0 + row) * D_;
        float x[4];
        float s = 0.f;
#pragma unroll
        for (int i = 0; i < 4; ++i) {
            int idx = i * 64 + lane;
            x[i] = H[base + idx] + Gf[row][idx];
            s += x[i];
        }
#pragma unroll
        for (int off = 32; off; off >>= 1) s += __shfl_xor(s, off);
        float mu = s * (1.f / D_);
        float ss = 0.f;
#pragma unroll
        for (int i = 0; i < 4; ++i) { float d = x[i] - mu; ss += d * d; }
#pragma unroll
        for (int off = 32; off; off >>= 1) ss += __shfl_xor(ss, off);
        float rstd = rsqrtf(ss * (1.f / D_) + 1e-5f);
#pragma unroll
        for (int i = 0; i < 4; ++i) {
            int idx = i * 64 + lane;
            float h1v = (x[i] - mu) * rstd * ln1w[idx] + ln1b[idx];
            Gf[row][idx] = h1v;
            h1b[row * HSTR + idx] = f2bf(h1v);
        }
    }
    __syncthreads();

    // ---- phase B: F = relu(h1 @ W1^T + b1)
    for (int nh = 0; nh < 2; ++nh) {
        const short* Wh = W1bf + (size_t)nh * 256 * 256;
        f32x4 acc1[2] = {};
#pragma unroll
        for (int u = 0; u < 4; ++u)
            wreg[u] = *(const s16x8*)&Wh[(size_t)(wrow + u * 64) * 256 + wc8];
        for (int k0 = 0; k0 < 256; k0 += 64) {
#pragma unroll
            for (int u = 0; u < 4; ++u)
                *(s16x8*)&Ws[(wrow + u * 64) * WSTR + wc8] = wreg[u];
            __syncthreads();
            int kn = k0 + 64;
            if (kn < 256) {
#pragma unroll
                for (int u = 0; u < 4; ++u)
                    wreg[u] = *(const s16x8*)&Wh[(size_t)(wrow + u * 64) * 256 + kn + wc8];
            }
#pragma unroll
            for (int s = 0; s < 2; ++s) {
                s16x8 af = *(const s16x8*)&h1b[lr * HSTR + k0 + s * 32 + lg * 8];
#pragma unroll
                for (int j = 0; j < 2; ++j) {
                    s16x8 wf = *(const s16x8*)&Ws[(wave * 32 + j * 16 + lr) * WSTR + s * 32 + lg * 8];
                    acc1[j] = __builtin_amdgcn_mfma_f32_16x16x32_bf16(af, wf, acc1[j], 0, 0, 0);
                }
            }
            __syncthreads();
        }
#pragma unroll
        for (int j = 0; j < 2; ++j) {
            int col = nh * 256 + wave * 32 + j * 16 + lr;
            float bv = b1[col];
#pragma unroll
            for (int q = 0; q < 4; ++q)
                Fs[(lg * 4 + q) * FSTR + col] = f2bf(fmaxf(acc1[j][q] + bv, 0.f));
        }
        __syncthreads();
    }

    // ---- phase C: G2 = F @ W2^T + b2
    f32x4 acc2[2] = {};
#pragma unroll
    for (int u = 0; u < 4; ++u)
        wreg[u] = *(const s16x8*)&W2bf[(size_t)(wrow + u * 64) * 512 + wc8];
    for (int k0 = 0; k0 < 512; k0 += 64) {
#pragma unroll
        for (int u = 0; u < 4; ++u)
            *(s16x8*)&Ws[(wrow + u * 64) * WSTR + wc8] = wreg[u];
        __syncthreads();
        int kn = k0 + 64;
        if (kn < 512) {
#pragma unroll
            for (int u = 0; u < 4; ++u)
                wreg[u] = *(const s16x8*)&W2bf[(size_t)(wrow + u * 64) * 512 + kn + wc8];
        }
#pragma unroll
        for (int s = 0; s < 2; ++s) {
            s16x8 af = *(const s16x8*)&Fs[lr * FSTR + k0 + s * 32 + lg * 8];
#pragma unroll
            for (int j = 0; j < 2; ++j) {
                s16x8 wf = *(const s16x8*)&Ws[(wave * 32 + j * 16 + lr) * WSTR + s * 32 + lg * 8];
                acc2[j] = __builtin_amdgcn_mfma_f32_16x16x32_bf16(af, wf, acc2[j], 0, 0, 0);
            }
        }
        __syncthreads();
    }
#pragma unroll
    for (int j = 0; j < 2; ++j) {
        int col = wave * 32 + j * 16 + lr;
        float bv = b2[col];
#pragma unroll
        for (int q = 0; q < 4; ++q)
            G2[lg * 4 + q][col] = acc2[j][q] + bv;
    }
    __syncthreads();

    // ---- LN2
    for (int rr = 0; rr < 2; ++rr) {
        int row = wave * 2 + rr;
        size_t base = (size_t)(m0 + row) * D_;
        float x[4];
        float s = 0.f;
#pragma unroll
        for (int i = 0; i < 4; ++i) {
            int idx = i * 64 + lane;
            x[i] = Gf[row][idx] + G2[row][idx];
            s += x[i];
        }
#pragma unroll
        for (int off = 32; off; off >>= 1) s += __shfl_xor(s, off);
        float mu = s * (1.f / D_);
        float ss = 0.f;
#pragma unroll
        for (int i = 0; i < 4; ++i) { float d = x[i] - mu; ss += d * d; }
#pragma unroll
        for (int off = 32; off; off >>= 1) ss += __shfl_xor(ss, off);
        float rstd = rsqrtf(ss * (1.f / D_) + 1e-5f);
#pragma unroll
        for (int i = 0; i < 4; ++i) {
            int idx = i * 64 + lane;
            H[base + idx] = (x[i] - mu) * rstd * ln2w[idx] + ln2b[idx];
        }
    }
}

// ---------------- MFMA banded attention (bf16 in, bf16 out)
__global__ __launch_bounds__(256) void attn_mfma(
    const short* __restrict__ qkv, short* __restrict__ out) {
    int q0 = blockIdx.x * 64;
    int h = blockIdx.y, b = blockIdx.z;
    int tid = threadIdx.x;
    int wave = tid >> 6, lane = tid & 63;
    int lg = lane >> 4;
    int lr = lane & 15;
    const int j0 = q0 - 64;

    __shared__ short Qs[64][40];
    __shared__ short Ks[128][40];
    __shared__ short Vt[32][PSTR];
    __shared__ short Ps[64][PSTR];

#pragma unroll
    for (int u = 0; u < 2; ++u) {
        int task = tid + 256 * u;
        int r = task >> 3, c = (task & 7) * 4;
        *(s16x4*)&Qs[r][c] =
            *(const s16x4*)&qkv[((size_t)(b * T_ + q0 + r)) * 768 + h * 32 + c];
    }
#pragma unroll
    for (int u = 0; u < 4; ++u) {
        int task = tid + 256 * u;
        int r = task >> 3, c = (task & 7) * 4;
        int jg = j0 + r;
        s16x4 sa = {0, 0, 0, 0};
        if (jg >= 0)
            sa = *(const s16x4*)&qkv[((size_t)(b * T_ + jg)) * 768 + 256 + h * 32 + c];
        *(s16x4*)&Ks[r][c] = sa;
    }
#pragma unroll
    for (int u = 0; u < 4; ++u) {
        int task = tid + 256 * u;
        int r = task >> 3, c = (task & 7) * 4;
        int jg = j0 + r;
        s16x4 v4 = {0, 0, 0, 0};
        if (jg >= 0)
            v4 = *(const s16x4*)&qkv[((size_t)(b * T_ + jg)) * 768 + 512 + h * 32 + c];
        Vt[c + 0][r] = v4[0];
        Vt[c + 1][r] = v4[1];
        Vt[c + 2][r] = v4[2];
        Vt[c + 3][r] = v4[3];
    }
    __syncthreads();

    s16x8 aq = *(const s16x8*)&Qs[16 * wave + lr][lg * 8];
    f32x4 sacc[8];
#pragma unroll
    for (int j = 0; j < 8; ++j) {
        s16x8 bk = *(const s16x8*)&Ks[16 * j + lr][lg * 8];
        f32x4 z = {0.f, 0.f, 0.f, 0.f};
        sacc[j] = __builtin_amdgcn_mfma_f32_16x16x32_bf16(aq, bk, z, 0, 0, 0);
    }

    const float scale = 0.17677669529663687f;
#pragma unroll
    for (int j = 0; j < 8; ++j) {
        int jg = j0 + 16 * j + lr;
#pragma unroll
        for (int q = 0; q < 4; ++q) {
            int qi = q0 + 16 * wave + lg * 4 + q;
            bool ok = ((jg >= qi - WIN_) && (jg < qi) && (jg >= 0)) || (qi == 0 && jg == 0);
            sacc[j][q] = ok ? sacc[j][q] * scale : -1e30f;
        }
    }
#pragma unroll
    for (int q = 0; q < 4; ++q) {
        float m = sacc[0][q];
#pragma unroll
        for (int j = 1; j < 8; ++j) m = fmaxf(m, sacc[j][q]);
#pragma unroll
        for (int off = 1; off < 16; off <<= 1) m = fmaxf(m, __shfl_xor(m, off));
        float e[8], sum = 0.f;
#pragma unroll
        for (int j = 0; j < 8; ++j) { e[j] = __expf(sacc[j][q] - m); sum += e[j]; }
#pragma unroll
        for (int off = 1; off < 16; off <<= 1) sum += __shfl_xor(sum, off);
        float inv = 1.f / sum;
        int row = 16 * wave + lg * 4 + q;
#pragma unroll
        for (int j = 0; j < 8; ++j) Ps[row][16 * j + lr] = f2bf(e[j] * inv);
    }

    f32x4 oacc[2] = {};
#pragma unroll
    for (int kk = 0; kk < 4; ++kk) {
        s16x8 ap = *(const s16x8*)&Ps[16 * wave + lr][kk * 32 + lg * 8];
#pragma unroll
        for (int n = 0; n < 2; ++n) {
            s16x8 bv = *(const s16x8*)&Vt[16 * n + lr][kk * 32 + lg * 8];
            oacc[n] = __builtin_amdgcn_mfma_f32_16x16x32_bf16(ap, bv, oacc[n], 0, 0, 0);
        }
    }
#pragma unroll
    for (int n = 0; n < 2; ++n)
#pragma unroll
        for (int q = 0; q < 4; ++q) {
            int qi = q0 + 16 * wave + lg * 4 + q;
            out[((size_t)(b * T_ + qi)) * D_ + h * 32 + 16 * n + lr] = f2bf(oacc[n][q]);
        }
}

// ---------------- LN2d apply + ReLU (float4); stats reduced from part2 in-kernel
__global__ __launch_bounds__(256) void ln2d_apply(
    const float* __restrict__ x, const float* __restrict__ w,
    const float* __restrict__ bb, const float* __restrict__ part2,
    float* __restrict__ y, int CT, int npart) {
    int b = blockIdx.y;
    int tid = threadIdx.x;
    __shared__ float sstat[2];
    if (tid < 64) {
        float s = 0.f, ss = 0.f;
        const float2* p2 = (const float2*)part2 + (size_t)b * npart;
        for (int i = tid; i < npart; i += 64) { float2 v = p2[i]; s += v.x; ss += v.y; }
#pragma unroll
        for (int off = 32; off; off >>= 1) {
            s += __shfl_xor(s, off);
            ss += __shfl_xor(ss, off);
        }
        if (tid == 0) {
            float mu = s / (float)CT;
            sstat[0] = mu;
            sstat[1] = rsqrtf(ss / (float)CT - mu * mu + 1e-5f);
        }
    }
    __syncthreads();
    float mu = sstat[0], rstd = sstat[1];
    int idx = blockIdx.x * 256 + tid;
    const float4* x4 = (const float4*)(x + (size_t)b * CT);
    const float4* w4 = (const float4*)w;
    const float4* b4 = (const float4*)bb;
    float4* y4 = (float4*)(y + (size_t)b * CT);
    float4 v = x4[idx], wv = w4[idx], bv = b4[idx];
    float4 r;
    r.x = fmaxf((v.x - mu) * rstd * wv.x + bv.x, 0.f);
    r.y = fmaxf((v.y - mu) * rstd * wv.y + bv.y, 0.f);
    r.z = fmaxf((v.z - mu) * rstd * wv.z + bv.z, 0.f);
    r.w = fmaxf((v.w - mu) * rstd * wv.w + bv.w, 0.f);
    y4[idx] = r;
}

// ---------------- LN2d apply + ReLU + transpose + pos add: [B,D,T] -> [B,T,D]
__global__ __launch_bounds__(256) void ln2d_apply_t(
    const float* __restrict__ x, const float* __restrict__ w,
    const float* __restrict__ bb, const float* __restrict__ part2,
    const float* __restrict__ pos, float* __restrict__ h, int npart) {
    int t0 = blockIdx.x * 32;
    int d0 = blockIdx.y * 32;
    int b = blockIdx.z;
    int tid = threadIdx.x;
    __shared__ float sstat[2];
    if (tid < 64) {
        float s = 0.f, ss = 0.f;
        const float2* p2 = (const float2*)part2 + (size_t)b * npart;
        for (int i = tid; i < npart; i += 64) { float2 v = p2[i]; s += v.x; ss += v.y; }
#pragma unroll
        for (int off = 32; off; off >>= 1) {
            s += __shfl_xor(s, off);
            ss += __shfl_xor(ss, off);
        }
        if (tid == 0) {
            float mu = s / (float)(D_ * T_);
            sstat[0] = mu;
            sstat[1] = rsqrtf(ss / (float)(D_ * T_) - mu * mu + 1e-5f);
        }
    }
    __syncthreads();
    float mu = sstat[0], rstd = sstat[1];
    __shared__ float xs[32][33];
    int tt = tid & 31, dd = tid >> 5;
#pragma unroll
    for (int p = 0; p < 4; ++p) {
        int d = d0 + dd + p * 8;
        size_t off = ((size_t)b * D_ + d) * T_ + t0 + tt;
        size_t woff = (size_t)d * T_ + t0 + tt;
        float v = (x[off] - mu) * rstd * w[woff] + bb[woff];
        xs[dd + p * 8][tt] = fmaxf(v, 0.f);
    }
    __syncthreads();
    int dd2 = tid & 31, tt2 = tid >> 5;
#pragma unroll
    for (int p = 0; p < 4; ++p) {
        int t = t0 + tt2 + p * 8;
        h[((size_t)(b * T_ + t)) * D_ + d0 + dd2] =
            xs[dd2][tt2 + p * 8] + pos[(size_t)t * D_ + d0 + dd2];
    }
}

extern "C" void kernel_launch(void* const* d_in, const int* in_sizes, int n_in,
                              void* d_out, int out_size, void* d_ws, size_t ws_size,
                              hipStream_t stream) {
    const float* x        = (const float*)d_in[0];
    const float* pre_w0   = (const float*)d_in[1];
    const float* pre_b0   = (const float*)d_in[2];
    const float* pre_lnw0 = (const float*)d_in[3];
    const float* pre_lnb0 = (const float*)d_in[4];
    const float* pre_w1   = (const float*)d_in[5];
    const float* pre_b1   = (const float*)d_in[6];
    const float* pre_lnw1 = (const float*)d_in[7];
    const float* pre_lnb1 = (const float*)d_in[8];
    const float* pos_emb  = (const float*)d_in[9];
    const float* Wqkv     = (const float*)d_in[10];
    const float* bqkv     = (const float*)d_in[11];
    const float* Wo       = (const float*)d_in[12];
    const float* bo       = (const float*)d_in[13];
    const float* ln1w     = (const float*)d_in[14];
    const float* ln1b     = (const float*)d_in[15];
    const float* W1       = (const float*)d_in[16];
    const float* b1       = (const float*)d_in[17];
    const float* W2       = (const float*)d_in[18];
    const float* b2       = (const float*)d_in[19];
    const float* ln2w     = (const float*)d_in[20];
    const float* ln2b     = (const float*)d_in[21];
    const float* post_w0  = (const float*)d_in[22];
    const float* post_b0  = (const float*)d_in[23];
    const float* post_lnw0= (const float*)d_in[24];
    const float* post_lnb0= (const float*)d_in[25];
    const float* post_w1  = (const float*)d_in[26];
    const float* post_b1  = (const float*)d_in[27];
    const float* post_lnw1= (const float*)d_in[28];
    const float* post_lnb1= (const float*)d_in[29];

    float* ws = (float*)d_ws;
    const size_t M1 = 1u << 20;              // 1M floats
    float* H     = ws;                       // [B,T,D] fp32
    float* A0    = ws + 1 * M1;              // [B,D,T] fp32 (pre/post only)
    float* A1    = ws + 2 * M1;              // [B,D,T] fp32 (pre/post only)
    short* QKVb  = (short*)(ws + 1 * M1);    // [B,T,768] bf16 (aliases A0/A1)
    short* ATTb  = (short*)(ws + 5 * M1);    // [B,T,256] bf16
    short* wbf   = (short*)(ws + 6 * M1);    // transformer weights bf16
    short* wqkv_bf = wbf;
    short* wo_bf   = wbf + 786432;
    short* w1_bf   = wbf + 1048576;
    short* w2_bf   = wbf + 1572864;
    short* cwbf  = wbf + 2097152;            // conv weights reordered
    short* cw_pre0  = cwbf;                  // [256][3*128]
    short* cw_pre1  = cwbf + 98304;          // [256][3*256]
    short* cw_post0 = cwbf + 294912;         // [256][3*256]
    short* cw_post1 = cwbf + 491520;         // [128][3*256]
    float* part2 = ws + 8 * M1;              // up to 4*256*2 floats

    const int M = B_ * T_;  // 4096

    // ---- one-time weight prep
    prep_w<<<2048, 256, 0, stream>>>(Wqkv, Wo, W1, W2,
                                     pre_w0, pre_w1, post_w0, post_w1, wbf);

    // ---- pre stage
    gemm_conv16<128, 0><<<dim3(D_ / 64, M / 16), 256, 0, stream>>>(
        x, cw_pre0, pre_b0, A0, D_, part2);
    ln2d_apply<<<dim3(D_ * T_ / 1024, B_), 256, 0, stream>>>(
        A0, pre_lnw0, pre_lnb0, part2, A1, D_ * T_, 256);
    gemm_conv16<256, 0><<<dim3(D_ / 64, M / 16), 256, 0, stream>>>(
        A1, cw_pre1, pre_b1, A0, D_, part2);
    ln2d_apply_t<<<dim3(T_ / 32, D_ / 32, B_), 256, 0, stream>>>(
        A0, pre_lnw1, pre_lnb1, part2, pos_emb, H, 256);

    // ---- transformer layers (3 dispatches each)
    for (int l = 0; l < L_; ++l) {
        gemm64w<0, 1><<<dim3(768 / 64, M / 64), 256, 0, stream>>>(
            H, wqkv_bf + (size_t)l * 196608, bqkv + (size_t)l * 768, QKVb, M, 768, D_);
        attn_mfma<<<dim3(T_ / 64, H_, B_), 256, 0, stream>>>(QKVb, ATTb);
        layer_tail<<<M / 16, 512, 0, stream>>>(
            ATTb, wo_bf + (size_t)l * 65536, bo + (size_t)l * D_,
            w1_bf + (size_t)l * 131072, b1 + (size_t)l * DFF_,
            w2_bf + (size_t)l * 131072, b2 + (size_t)l * D_, H,
            ln1w + (size_t)l * D_, ln1b + (size_t)l * D_,
            ln2w + (size_t)l * D_, ln2b + (size_t)l * D_);
    }

    // ---- post stage
    gemm_conv16<256, 1><<<dim3(D_ / 64, M / 16), 256, 0, stream>>>(
        H, cw_post0, post_b0, A1, D_, part2);
    ln2d_apply<<<dim3(D_ * T_ / 1024, B_), 256, 0, stream>>>(
        A1, post_lnw0, post_lnb0, part2, A0, D_ * T_, 256);
    gemm_conv16<256, 0><<<dim3(CIN_ / 64, M / 16), 256, 0, stream>>>(
        A0, cw_post1, post_b1, A1, CIN_, part2);
    ln2d_apply<<<dim3(CIN_ * T_ / 1024, B_), 256, 0, stream>>>(
        A1, post_lnw1, post_lnb1, part2, (float*)d_out, CIN_ * T_, 128);
}

// Round 21
// 214.399 us; speedup vs baseline: 1.1032x; 1.0364x over previous
//
#include <hip/hip_runtime.h>
#include <hip/hip_bf16.h>

#define B_ 4
#define T_ 1024
#define D_ 256
#define H_ 8
#define WIN_ 64
#define CIN_ 128
#define DH_ 32
#define DFF_ 512
#define L_ 4
#define PSTR 152 // attn Ps/Vt LDS row stride (shorts)
#define FSTR 520 // ffn F-tile LDS row stride (shorts)
#define HSTR 264 // h1 bf16 LDS row stride (shorts)
#define WSTR 72  // BK=64 weight/A tile row stride (shorts)
#define W2STR 136 // BK=128 weight/A tile row stride (shorts, layer_tail)

typedef __attribute__((ext_vector_type(4))) short s16x4;
typedef __attribute__((ext_vector_type(8))) short s16x8;
typedef __attribute__((ext_vector_type(4))) float f32x4;

__device__ inline short f2bf(float f) {
    __hip_bfloat16 h = __float2bfloat16(f);
    return *reinterpret_cast<short*>(&h);
}

// ---------------- one-time weight prep
__global__ __launch_bounds__(256) void prep_w(
    const float* __restrict__ wqkv, const float* __restrict__ wo,
    const float* __restrict__ w1, const float* __restrict__ w2,
    const float* __restrict__ pw0, const float* __restrict__ pw1,
    const float* __restrict__ qw0, const float* __restrict__ qw1,
    short* __restrict__ dst) {
    const int N0 = 786432, N1 = 1048576, N2 = 1572864, NT = 2097152;
    const int NTOT = 2686976;
    for (int i = blockIdx.x * 256 + threadIdx.x; i < NTOT; i += gridDim.x * 256) {
        float v;
        if (i < NT) {
            if (i < N0) v = wqkv[i];
            else if (i < N1) v = wo[i - N0];
            else if (i < N2) v = w1[i - N1];
            else v = w2[i - N2];
        } else {
            int j = i - NT;
            const float* src;
            int I;
            if (j < 98304)       { src = pw0; I = 128; }
            else if (j < 294912) { src = pw1; I = 256; j -= 98304; }
            else if (j < 491520) { src = qw0; I = 256; j -= 294912; }
            else                 { src = qw1; I = 256; j -= 491520; }
            int o = j / (3 * I);
            int rem = j - o * 3 * I;
            int k = rem / I, ii = rem - k * I;
            v = src[(size_t)(o * I + ii) * 3 + k];
        }
        dst[i] = f2bf(v);
    }
}

// ---------------- fused im2col + conv-GEMM + LN2d-partial, 16x64 tile, BK=64,
// register-prefetched (T14)
template <int I_, int BTD>
__global__ __launch_bounds__(256) void gemm_conv16(
    const float* __restrict__ x, const short* __restrict__ Wr,
    const float* __restrict__ bias, float* __restrict__ Y, int O,
    float* __restrict__ part2) {
    const int K = 3 * I_;
    __shared__ short Al[16 * WSTR];
    __shared__ short Wl[64 * WSTR];
    __shared__ float sh[8];
    int tid = threadIdx.x;
    int col0 = blockIdx.x * 64;
    int row0 = blockIdx.y * 16;
    int b = row0 >> 10, t0 = row0 & 1023;
    int wave = tid >> 6, lane = tid & 63;
    int lg = lane >> 4, lr = lane & 15;
    f32x4 acc = {0.f, 0.f, 0.f, 0.f};

    float areg[4];
    s16x4 wreg[4];

    // prologue: chunk 0
    {
        int k = 0, i0 = 0;
#pragma unroll
        for (int p = 0; p < 4; ++p) {
            int e = p * 256 + tid;
            int rr, cc;
            if (BTD) { rr = e >> 6; cc = e & 63; }
            else     { cc = e >> 4; rr = e & 15; }
            int tg = t0 + rr - 1 + k;
            areg[p] = (tg >= 0 && tg < T_)
                          ? (BTD ? x[((size_t)(b * T_ + tg)) * I_ + i0 + cc]
                                 : x[((size_t)(b * I_ + i0 + cc)) * T_ + tg])
                          : 0.f;
        }
#pragma unroll
        for (int p = 0; p < 4; ++p) {
            int e = p * 256 + tid;
            int rr = e >> 4, c4 = (e & 15) * 4;
            wreg[p] = *(const s16x4*)&Wr[(size_t)(col0 + rr) * K + c4];
        }
    }

    for (int k0 = 0; k0 < K; k0 += 64) {
#pragma unroll
        for (int p = 0; p < 4; ++p) {
            int e = p * 256 + tid;
            int rr, cc;
            if (BTD) { rr = e >> 6; cc = e & 63; }
            else     { cc = e >> 4; rr = e & 15; }
            Al[rr * WSTR + cc] = f2bf(areg[p]);
        }
#pragma unroll
        for (int p = 0; p < 4; ++p) {
            int e = p * 256 + tid;
            int rr = e >> 4, c4 = (e & 15) * 4;
            *(s16x4*)&Wl[rr * WSTR + c4] = wreg[p];
        }
        __syncthreads();
        int kn = k0 + 64;
        if (kn < K) {
            int k = kn / I_;
            int i0 = kn - k * I_;
#pragma unroll
            for (int p = 0; p < 4; ++p) {
                int e = p * 256 + tid;
                int rr, cc;
                if (BTD) { rr = e >> 6; cc = e & 63; }
                else     { cc = e >> 4; rr = e & 15; }
                int tg = t0 + rr - 1 + k;
                areg[p] = (tg >= 0 && tg < T_)
                              ? (BTD ? x[((size_t)(b * T_ + tg)) * I_ + i0 + cc]
                                     : x[((size_t)(b * I_ + i0 + cc)) * T_ + tg])
                              : 0.f;
            }
#pragma unroll
            for (int p = 0; p < 4; ++p) {
                int e = p * 256 + tid;
                int rr = e >> 4, c4 = (e & 15) * 4;
                wreg[p] = *(const s16x4*)&Wr[(size_t)(col0 + rr) * K + kn + c4];
            }
        }
        s16x8 af0 = *(const s16x8*)&Al[lr * WSTR + lg * 8];
        s16x8 af1 = *(const s16x8*)&Al[lr * WSTR + 32 + lg * 8];
        s16x8 wf0 = *(const s16x8*)&Wl[(wave * 16 + lr) * WSTR + lg * 8];
        s16x8 wf1 = *(const s16x8*)&Wl[(wave * 16 + lr) * WSTR + 32 + lg * 8];
        acc = __builtin_amdgcn_mfma_f32_16x16x32_bf16(af0, wf0, acc, 0, 0, 0);
        acc = __builtin_amdgcn_mfma_f32_16x16x32_bf16(af1, wf1, acc, 0, 0, 0);
        __syncthreads();
    }

    int cg = col0 + wave * 16 + lr;
    float bv = bias[cg];
    float4 o;
    o.x = acc[0] + bv; o.y = acc[1] + bv; o.z = acc[2] + bv; o.w = acc[3] + bv;
    *(float4*)&Y[((size_t)(b * O + cg)) * 1024 + t0 + lg * 4] = o;

    float s = o.x + o.y + o.z + o.w;
    float ss = o.x * o.x + o.y * o.y + o.z * o.z + o.w * o.w;
#pragma unroll
    for (int off = 32; off; off >>= 1) {
        s += __shfl_xor(s, off);
        ss += __shfl_xor(ss, off);
    }
    if (lane == 0) { sh[wave * 2] = s; sh[wave * 2 + 1] = ss; }
    __syncthreads();
    if (tid == 0) {
        float ts = sh[0] + sh[2] + sh[4] + sh[6];
        float tss = sh[1] + sh[3] + sh[5] + sh[7];
        int slot = b * (gridDim.x * 64) + blockIdx.x * 64 + (blockIdx.y & 63);
        part2[slot * 2] = ts;
        part2[slot * 2 + 1] = tss;
    }
}

// ---------------- bf16-weight MFMA GEMM (QKV), 64x64 tile, BK=64, prefetched
template <int RELU, int BF16OUT>
__global__ __launch_bounds__(256) void gemm64w(
    const float* __restrict__ A, const short* __restrict__ Wbf,
    const float* __restrict__ bias, void* __restrict__ Yv,
    int M, int N, int K) {
    __shared__ short Al[64 * WSTR];
    __shared__ short Wl[64 * WSTR];
    int tid = threadIdx.x;
    int row0 = blockIdx.y * 64, col0 = blockIdx.x * 64;
    int wave = tid >> 6, lane = tid & 63;
    int wr = wave >> 1, wc = wave & 1;
    int lg = lane >> 4, lr = lane & 15;
    f32x4 acc[2][2] = {};

    float4 areg[4];
    s16x4 wreg[4];
#pragma unroll
    for (int p = 0; p < 4; ++p) {
        int e = p * 256 + tid;
        int rr = e >> 4, c4 = (e & 15) * 4;
        areg[p] = *(const float4*)&A[(size_t)(row0 + rr) * K + c4];
        wreg[p] = *(const s16x4*)&Wbf[(size_t)(col0 + rr) * K + c4];
    }

    for (int k0 = 0; k0 < K; k0 += 64) {
#pragma unroll
        for (int p = 0; p < 4; ++p) {
            int e = p * 256 + tid;
            int rr = e >> 4, c4 = (e & 15) * 4;
            s16x4 sa;
            sa[0] = f2bf(areg[p].x); sa[1] = f2bf(areg[p].y);
            sa[2] = f2bf(areg[p].z); sa[3] = f2bf(areg[p].w);
            *(s16x4*)&Al[rr * WSTR + c4] = sa;
            *(s16x4*)&Wl[rr * WSTR + c4] = wreg[p];
        }
        __syncthreads();
        int kn = k0 + 64;
        if (kn < K) {
#pragma unroll
            for (int p = 0; p < 4; ++p) {
                int e = p * 256 + tid;
                int rr = e >> 4, c4 = (e & 15) * 4;
                areg[p] = *(const float4*)&A[(size_t)(row0 + rr) * K + kn + c4];
                wreg[p] = *(const s16x4*)&Wbf[(size_t)(col0 + rr) * K + kn + c4];
            }
        }
#pragma unroll
        for (int s = 0; s < 2; ++s) {
            s16x8 af[2], wf[2];
#pragma unroll
            for (int i = 0; i < 2; ++i) {
                af[i] = *(const s16x8*)&Al[(wr * 32 + i * 16 + lr) * WSTR + s * 32 + lg * 8];
                wf[i] = *(const s16x8*)&Wl[(wc * 32 + i * 16 + lr) * WSTR + s * 32 + lg * 8];
            }
#pragma unroll
            for (int i = 0; i < 2; ++i)
#pragma unroll
                for (int j = 0; j < 2; ++j)
                    acc[i][j] = __builtin_amdgcn_mfma_f32_16x16x32_bf16(af[i], wf[j], acc[i][j], 0, 0, 0);
        }
        __syncthreads();
    }
#pragma unroll
    for (int i = 0; i < 2; ++i) {
        int rg = row0 + wr * 32 + i * 16 + lg * 4;
#pragma unroll
        for (int j = 0; j < 2; ++j) {
            int cg = col0 + wc * 32 + j * 16 + lr;
            float bv = bias[cg];
#pragma unroll
            for (int q = 0; q < 4; ++q) {
                float v = acc[i][j][q] + bv;
                if (RELU) v = fmaxf(v, 0.f);
                if (BF16OUT) ((short*)Yv)[(size_t)(rg + q) * N + cg] = f2bf(v);
                else ((float*)Yv)[(size_t)(rg + q) * N + cg] = v;
            }
        }
    }
}

// ---------------- fused layer tail, BK=128 + register prefetch (T14)
// Same ordered MFMA sequence as BK=64 version -> bit-identical.
__global__ __launch_bounds__(512) void layer_tail(
    const short* __restrict__ ATTb, const short* __restrict__ Wobf,
    const float* __restrict__ bo, const short* __restrict__ W1bf,
    const float* __restrict__ b1, const short* __restrict__ W2bf,
    const float* __restrict__ b2, float* __restrict__ H,
    const float* __restrict__ ln1w, const float* __restrict__ ln1b,
    const float* __restrict__ ln2w, const float* __restrict__ ln2b) {
    __shared__ short As[16 * W2STR];    // 16x128 A tile
    __shared__ short Ws[256 * W2STR];   // 256x128 weight stage (68 KB)
    __shared__ float Gf[16][260];
    __shared__ short h1b[16 * HSTR];
    __shared__ short Fs[16 * FSTR];
    __shared__ float G2[16][260];
    int tid = threadIdx.x;
    int wave = tid >> 6, lane = tid & 63;
    int lg = lane >> 4, lr = lane & 15;
    int m0 = blockIdx.x * 16;

    int wrow = tid >> 4, wc8 = (tid & 15) * 8;   // Ws: 4096 s16x8 tasks, 8/thread (+32-row steps)
    int arow = tid >> 5, ac4 = (tid & 31) * 4;   // As: 512 s16x4 tasks, 1/thread

    s16x8 wreg[8];
    s16x4 areg;

    // ---- phase A: G1 = ATT @ Wo^T + bo   (K=256, 2 iters of 128)
    f32x4 accA[2] = {};
    areg = *(const s16x4*)&ATTb[(size_t)(m0 + arow) * 256 + ac4];
#pragma unroll
    for (int u = 0; u < 8; ++u)
        wreg[u] = *(const s16x8*)&Wobf[(size_t)(wrow + u * 32) * 256 + wc8];
    for (int k0 = 0; k0 < 256; k0 += 128) {
        *(s16x4*)&As[arow * W2STR + ac4] = areg;
#pragma unroll
        for (int u = 0; u < 8; ++u)
            *(s16x8*)&Ws[(wrow + u * 32) * W2STR + wc8] = wreg[u];
        __syncthreads();
        int kn = k0 + 128;
        if (kn < 256) {
            areg = *(const s16x4*)&ATTb[(size_t)(m0 + arow) * 256 + kn + ac4];
#pragma unroll
            for (int u = 0; u < 8; ++u)
                wreg[u] = *(const s16x8*)&Wobf[(size_t)(wrow + u * 32) * 256 + kn + wc8];
        }
#pragma unroll
        for (int s = 0; s < 4; ++s) {
            s16x8 af = *(const s16x8*)&As[lr * W2STR + s * 32 + lg * 8];
#pragma unroll
            for (int j = 0; j < 2; ++j) {
                s16x8 wf = *(const s16x8*)&Ws[(wave * 32 + j * 16 + lr) * W2STR + s * 32 + lg * 8];
                accA[j] = __builtin_amdgcn_mfma_f32_16x16x32_bf16(af, wf, accA[j], 0, 0, 0);
            }
        }
        __syncthreads();
    }
#pragma unroll
    for (int j = 0; j < 2; ++j) {
        int col = wave * 32 + j * 16 + lr;
        float bv = bo[col];
#pragma unroll
        for (int q = 0; q < 4; ++q)
            Gf[lg * 4 + q][col] = accA[j][q] + bv;
    }
    __syncthreads();

    // ---- LN1
    for (int rr = 0; rr < 2; ++rr) {
        int row = wave * 2 + rr;
        size_t base = (size_t)(m0 + row) * D_;
        float x[4];
        float s = 0.f;
#pragma unroll
        for (int i = 0; i < 4; ++i) {
            int idx = i * 64 + lane;
            x[i] = H[base + idx] + Gf[row][idx];
            s += x[i];
        }
#pragma unroll
        for (int off = 32; off; off >>= 1) s += __shfl_xor(s, off);
        float mu = s * (1.f / D_);
        float ss = 0.f;
#pragma unroll
        for (int i = 0; i < 4; ++i) { float d = x[i] - mu; ss += d * d; }
#pragma unroll
        for (int off = 32; off; off >>= 1) ss += __shfl_xor(ss, off);
        float rstd = rsqrtf(ss * (1.f / D_) + 1e-5f);
#pragma unroll
        for (int i = 0; i < 4; ++i) {
            int idx = i * 64 + lane;
            float h1v = (x[i] - mu) * rstd * ln1w[idx] + ln1b[idx];
            Gf[row][idx] = h1v;
            h1b[row * HSTR + idx] = f2bf(h1v);
        }
    }
    __syncthreads();

    // ---- phase B: F = relu(h1 @ W1^T + b1)  (two 256-col halves, 2 iters each)
    for (int nh = 0; nh < 2; ++nh) {
        const short* Wh = W1bf + (size_t)nh * 256 * 256;
        f32x4 acc1[2] = {};
#pragma unroll
        for (int u = 0; u < 8; ++u)
            wreg[u] = *(const s16x8*)&Wh[(size_t)(wrow + u * 32) * 256 + wc8];
        for (int k0 = 0; k0 < 256; k0 += 128) {
#pragma unroll
            for (int u = 0; u < 8; ++u)
                *(s16x8*)&Ws[(wrow + u * 32) * W2STR + wc8] = wreg[u];
            __syncthreads();
            int kn = k0 + 128;
            if (kn < 256) {
#pragma unroll
                for (int u = 0; u < 8; ++u)
                    wreg[u] = *(const s16x8*)&Wh[(size_t)(wrow + u * 32) * 256 + kn + wc8];
            }
#pragma unroll
            for (int s = 0; s < 4; ++s) {
                s16x8 af = *(const s16x8*)&h1b[lr * HSTR + k0 + s * 32 + lg * 8];
#pragma unroll
                for (int j = 0; j < 2; ++j) {
                    s16x8 wf = *(const s16x8*)&Ws[(wave * 32 + j * 16 + lr) * W2STR + s * 32 + lg * 8];
                    acc1[j] = __builtin_amdgcn_mfma_f32_16x16x32_bf16(af, wf, acc1[j], 0, 0, 0);
                }
            }
            __syncthreads();
        }
#pragma unroll
        for (int j = 0; j < 2; ++j) {
            int col = nh * 256 + wave * 32 + j * 16 + lr;
            float bv = b1[col];
#pragma unroll
            for (int q = 0; q < 4; ++q)
                Fs[(lg * 4 + q) * FSTR + col] = f2bf(fmaxf(acc1[j][q] + bv, 0.f));
        }
        __syncthreads();
    }

    // ---- phase C: G2 = F @ W2^T + b2  (K=512, 4 iters of 128)
    f32x4 acc2[2] = {};
#pragma unroll
    for (int u = 0; u < 8; ++u)
        wreg[u] = *(const s16x8*)&W2bf[(size_t)(wrow + u * 32) * 512 + wc8];
    for (int k0 = 0; k0 < 512; k0 += 128) {
#pragma unroll
        for (int u = 0; u < 8; ++u)
            *(s16x8*)&Ws[(wrow + u * 32) * W2STR + wc8] = wreg[u];
        __syncthreads();
        int kn = k0 + 128;
        if (kn < 512) {
#pragma unroll
            for (int u = 0; u < 8; ++u)
                wreg[u] = *(const s16x8*)&W2bf[(size_t)(wrow + u * 32) * 512 + kn + wc8];
        }
#pragma unroll
        for (int s = 0; s < 4; ++s) {
            s16x8 af = *(const s16x8*)&Fs[lr * FSTR + k0 + s * 32 + lg * 8];
#pragma unroll
            for (int j = 0; j < 2; ++j) {
                s16x8 wf = *(const s16x8*)&Ws[(wave * 32 + j * 16 + lr) * W2STR + s * 32 + lg * 8];
                acc2[j] = __builtin_amdgcn_mfma_f32_16x16x32_bf16(af, wf, acc2[j], 0, 0, 0);
            }
        }
        __syncthreads();
    }
#pragma unroll
    for (int j = 0; j < 2; ++j) {
        int col = wave * 32 + j * 16 + lr;
        float bv = b2[col];
#pragma unroll
        for (int q = 0; q < 4; ++q)
            G2[lg * 4 + q][col] = acc2[j][q] + bv;
    }
    __syncthreads();

    // ---- LN2
    for (int rr = 0; rr < 2; ++rr) {
        int row = wave * 2 + rr;
        size_t base = (size_t)(m0 + row) * D_;
        float x[4];
        float s = 0.f;
#pragma unroll
        for (int i = 0; i < 4; ++i) {
            int idx = i * 64 + lane;
            x[i] = Gf[row][idx] + G2[row][idx];
            s += x[i];
        }
#pragma unroll
        for (int off = 32; off; off >>= 1) s += __shfl_xor(s, off);
        float mu = s * (1.f / D_);
        float ss = 0.f;
#pragma unroll
        for (int i = 0; i < 4; ++i) { float d = x[i] - mu; ss += d * d; }
#pragma unroll
        for (int off = 32; off; off >>= 1) ss += __shfl_xor(ss, off);
        float rstd = rsqrtf(ss * (1.f / D_) + 1e-5f);
#pragma unroll
        for (int i = 0; i < 4; ++i) {
            int idx = i * 64 + lane;
            H[base + idx] = (x[i] - mu) * rstd * ln2w[idx] + ln2b[idx];
        }
    }
}

// ---------------- MFMA banded attention (bf16 in, bf16 out)
__global__ __launch_bounds__(256) void attn_mfma(
    const short* __restrict__ qkv, short* __restrict__ out) {
    int q0 = blockIdx.x * 64;
    int h = blockIdx.y, b = blockIdx.z;
    int tid = threadIdx.x;
    int wave = tid >> 6, lane = tid & 63;
    int lg = lane >> 4;
    int lr = lane & 15;
    const int j0 = q0 - 64;

    __shared__ short Qs[64][40];
    __shared__ short Ks[128][40];
    __shared__ short Vt[32][PSTR];
    __shared__ short Ps[64][PSTR];

#pragma unroll
    for (int u = 0; u < 2; ++u) {
        int task = tid + 256 * u;
        int r = task >> 3, c = (task & 7) * 4;
        *(s16x4*)&Qs[r][c] =
            *(const s16x4*)&qkv[((size_t)(b * T_ + q0 + r)) * 768 + h * 32 + c];
    }
#pragma unroll
    for (int u = 0; u < 4; ++u) {
        int task = tid + 256 * u;
        int r = task >> 3, c = (task & 7) * 4;
        int jg = j0 + r;
        s16x4 sa = {0, 0, 0, 0};
        if (jg >= 0)
            sa = *(const s16x4*)&qkv[((size_t)(b * T_ + jg)) * 768 + 256 + h * 32 + c];
        *(s16x4*)&Ks[r][c] = sa;
    }
#pragma unroll
    for (int u = 0; u < 4; ++u) {
        int task = tid + 256 * u;
        int r = task >> 3, c = (task & 7) * 4;
        int jg = j0 + r;
        s16x4 v4 = {0, 0, 0, 0};
        if (jg >= 0)
            v4 = *(const s16x4*)&qkv[((size_t)(b * T_ + jg)) * 768 + 512 + h * 32 + c];
        Vt[c + 0][r] = v4[0];
        Vt[c + 1][r] = v4[1];
        Vt[c + 2][r] = v4[2];
        Vt[c + 3][r] = v4[3];
    }
    __syncthreads();

    s16x8 aq = *(const s16x8*)&Qs[16 * wave + lr][lg * 8];
    f32x4 sacc[8];
#pragma unroll
    for (int j = 0; j < 8; ++j) {
        s16x8 bk = *(const s16x8*)&Ks[16 * j + lr][lg * 8];
        f32x4 z = {0.f, 0.f, 0.f, 0.f};
        sacc[j] = __builtin_amdgcn_mfma_f32_16x16x32_bf16(aq, bk, z, 0, 0, 0);
    }

    const float scale = 0.17677669529663687f;
#pragma unroll
    for (int j = 0; j < 8; ++j) {
        int jg = j0 + 16 * j + lr;
#pragma unroll
        for (int q = 0; q < 4; ++q) {
            int qi = q0 + 16 * wave + lg * 4 + q;
            bool ok = ((jg >= qi - WIN_) && (jg < qi) && (jg >= 0)) || (qi == 0 && jg == 0);
            sacc[j][q] = ok ? sacc[j][q] * scale : -1e30f;
        }
    }
#pragma unroll
    for (int q = 0; q < 4; ++q) {
        float m = sacc[0][q];
#pragma unroll
        for (int j = 1; j < 8; ++j) m = fmaxf(m, sacc[j][q]);
#pragma unroll
        for (int off = 1; off < 16; off <<= 1) m = fmaxf(m, __shfl_xor(m, off));
        float e[8], sum = 0.f;
#pragma unroll
        for (int j = 0; j < 8; ++j) { e[j] = __expf(sacc[j][q] - m); sum += e[j]; }
#pragma unroll
        for (int off = 1; off < 16; off <<= 1) sum += __shfl_xor(sum, off);
        float inv = 1.f / sum;
        int row = 16 * wave + lg * 4 + q;
#pragma unroll
        for (int j = 0; j < 8; ++j) Ps[row][16 * j + lr] = f2bf(e[j] * inv);
    }

    f32x4 oacc[2] = {};
#pragma unroll
    for (int kk = 0; kk < 4; ++kk) {
        s16x8 ap = *(const s16x8*)&Ps[16 * wave + lr][kk * 32 + lg * 8];
#pragma unroll
        for (int n = 0; n < 2; ++n) {
            s16x8 bv = *(const s16x8*)&Vt[16 * n + lr][kk * 32 + lg * 8];
            oacc[n] = __builtin_amdgcn_mfma_f32_16x16x32_bf16(ap, bv, oacc[n], 0, 0, 0);
        }
    }
#pragma unroll
    for (int n = 0; n < 2; ++n)
#pragma unroll
        for (int q = 0; q < 4; ++q) {
            int qi = q0 + 16 * wave + lg * 4 + q;
            out[((size_t)(b * T_ + qi)) * D_ + h * 32 + 16 * n + lr] = f2bf(oacc[n][q]);
        }
}

// ---------------- LN2d apply + ReLU (float4); stats reduced from part2 in-kernel
__global__ __launch_bounds__(256) void ln2d_apply(
    const float* __restrict__ x, const float* __restrict__ w,
    const float* __restrict__ bb, const float* __restrict__ part2,
    float* __restrict__ y, int CT, int npart) {
    int b = blockIdx.y;
    int tid = threadIdx.x;
    __shared__ float sstat[2];
    if (tid < 64) {
        float s = 0.f, ss = 0.f;
        const float2* p2 = (const float2*)part2 + (size_t)b * npart;
        for (int i = tid; i < npart; i += 64) { float2 v = p2[i]; s += v.x; ss += v.y; }
#pragma unroll
        for (int off = 32; off; off >>= 1) {
            s += __shfl_xor(s, off);
            ss += __shfl_xor(ss, off);
        }
        if (tid == 0) {
            float mu = s / (float)CT;
            sstat[0] = mu;
            sstat[1] = rsqrtf(ss / (float)CT - mu * mu + 1e-5f);
        }
    }
    __syncthreads();
    float mu = sstat[0], rstd = sstat[1];
    int idx = blockIdx.x * 256 + tid;
    const float4* x4 = (const float4*)(x + (size_t)b * CT);
    const float4* w4 = (const float4*)w;
    const float4* b4 = (const float4*)bb;
    float4* y4 = (float4*)(y + (size_t)b * CT);
    float4 v = x4[idx], wv = w4[idx], bv = b4[idx];
    float4 r;
    r.x = fmaxf((v.x - mu) * rstd * wv.x + bv.x, 0.f);
    r.y = fmaxf((v.y - mu) * rstd * wv.y + bv.y, 0.f);
    r.z = fmaxf((v.z - mu) * rstd * wv.z + bv.z, 0.f);
    r.w = fmaxf((v.w - mu) * rstd * wv.w + bv.w, 0.f);
    y4[idx] = r;
}

// ---------------- LN2d apply + ReLU + transpose + pos add: [B,D,T] -> [B,T,D]
__global__ __launch_bounds__(256) void ln2d_apply_t(
    const float* __restrict__ x, const float* __restrict__ w,
    const float* __restrict__ bb, const float* __restrict__ part2,
    const float* __restrict__ pos, float* __restrict__ h, int npart) {
    int t0 = blockIdx.x * 32;
    int d0 = blockIdx.y * 32;
    int b = blockIdx.z;
    int tid = threadIdx.x;
    __shared__ float sstat[2];
    if (tid < 64) {
        float s = 0.f, ss = 0.f;
        const float2* p2 = (const float2*)part2 + (size_t)b * npart;
        for (int i = tid; i < npart; i += 64) { float2 v = p2[i]; s += v.x; ss += v.y; }
#pragma unroll
        for (int off = 32; off; off >>= 1) {
            s += __shfl_xor(s, off);
            ss += __shfl_xor(ss, off);
        }
        if (tid == 0) {
            float mu = s / (float)(D_ * T_);
            sstat[0] = mu;
            sstat[1] = rsqrtf(ss / (float)(D_ * T_) - mu * mu + 1e-5f);
        }
    }
    __syncthreads();
    float mu = sstat[0], rstd = sstat[1];
    __shared__ float xs[32][33];
    int tt = tid & 31, dd = tid >> 5;
#pragma unroll
    for (int p = 0; p < 4; ++p) {
        int d = d0 + dd + p * 8;
        size_t off = ((size_t)b * D_ + d) * T_ + t0 + tt;
        size_t woff = (size_t)d * T_ + t0 + tt;
        float v = (x[off] - mu) * rstd * w[woff] + bb[woff];
        xs[dd + p * 8][tt] = fmaxf(v, 0.f);
    }
    __syncthreads();
    int dd2 = tid & 31, tt2 = tid >> 5;
#pragma unroll
    for (int p = 0; p < 4; ++p) {
        int t = t0 + tt2 + p * 8;
        h[((size_t)(b * T_ + t)) * D_ + d0 + dd2] =
            xs[dd2][tt2 + p * 8] + pos[(size_t)t * D_ + d0 + dd2];
    }
}

extern "C" void kernel_launch(void* const* d_in, const int* in_sizes, int n_in,
                              void* d_out, int out_size, void* d_ws, size_t ws_size,
                              hipStream_t stream) {
    const float* x        = (const float*)d_in[0];
    const float* pre_w0   = (const float*)d_in[1];
    const float* pre_b0   = (const float*)d_in[2];
    const float* pre_lnw0 = (const float*)d_in[3];
    const float* pre_lnb0 = (const float*)d_in[4];
    const float* pre_w1   = (const float*)d_in[5];
    const float* pre_b1   = (const float*)d_in[6];
    const float* pre_lnw1 = (const float*)d_in[7];
    const float* pre_lnb1 = (const float*)d_in[8];
    const float* pos_emb  = (const float*)d_in[9];
    const float* Wqkv     = (const float*)d_in[10];
    const float* bqkv     = (const float*)d_in[11];
    const float* Wo       = (const float*)d_in[12];
    const float* bo       = (const float*)d_in[13];
    const float* ln1w     = (const float*)d_in[14];
    const float* ln1b     = (const float*)d_in[15];
    const float* W1       = (const float*)d_in[16];
    const float* b1       = (const float*)d_in[17];
    const float* W2       = (const float*)d_in[18];
    const float* b2       = (const float*)d_in[19];
    const float* ln2w     = (const float*)d_in[20];
    const float* ln2b     = (const float*)d_in[21];
    const float* post_w0  = (const float*)d_in[22];
    const float* post_b0  = (const float*)d_in[23];
    const float* post_lnw0= (const float*)d_in[24];
    const float* post_lnb0= (const float*)d_in[25];
    const float* post_w1  = (const float*)d_in[26];
    const float* post_b1  = (const float*)d_in[27];
    const float* post_lnw1= (const float*)d_in[28];
    const float* post_lnb1= (const float*)d_in[29];

    float* ws = (float*)d_ws;
    const size_t M1 = 1u << 20;              // 1M floats
    float* H     = ws;                       // [B,T,D] fp32
    float* A0    = ws + 1 * M1;              // [B,D,T] fp32 (pre/post only)
    float* A1    = ws + 2 * M1;              // [B,D,T] fp32 (pre/post only)
    short* QKVb  = (short*)(ws + 1 * M1);    // [B,T,768] bf16 (aliases A0/A1)
    short* ATTb  = (short*)(ws + 5 * M1);    // [B,T,256] bf16
    short* wbf   = (short*)(ws + 6 * M1);    // transformer weights bf16
    short* wqkv_bf = wbf;
    short* wo_bf   = wbf + 786432;
    short* w1_bf   = wbf + 1048576;
    short* w2_bf   = wbf + 1572864;
    short* cwbf  = wbf + 2097152;            // conv weights reordered
    short* cw_pre0  = cwbf;                  // [256][3*128]
    short* cw_pre1  = cwbf + 98304;          // [256][3*256]
    short* cw_post0 = cwbf + 294912;         // [256][3*256]
    short* cw_post1 = cwbf + 491520;         // [128][3*256]
    float* part2 = ws + 8 * M1;              // up to 4*256*2 floats

    const int M = B_ * T_;  // 4096

    // ---- one-time weight prep
    prep_w<<<2048, 256, 0, stream>>>(Wqkv, Wo, W1, W2,
                                     pre_w0, pre_w1, post_w0, post_w1, wbf);

    // ---- pre stage
    gemm_conv16<128, 0><<<dim3(D_ / 64, M / 16), 256, 0, stream>>>(
        x, cw_pre0, pre_b0, A0, D_, part2);
    ln2d_apply<<<dim3(D_ * T_ / 1024, B_), 256, 0, stream>>>(
        A0, pre_lnw0, pre_lnb0, part2, A1, D_ * T_, 256);
    gemm_conv16<256, 0><<<dim3(D_ / 64, M / 16), 256, 0, stream>>>(
        A1, cw_pre1, pre_b1, A0, D_, part2);
    ln2d_apply_t<<<dim3(T_ / 32, D_ / 32, B_), 256, 0, stream>>>(
        A0, pre_lnw1, pre_lnb1, part2, pos_emb, H, 256);

    // ---- transformer layers (3 dispatches each)
    for (int l = 0; l < L_; ++l) {
        gemm64w<0, 1><<<dim3(768 / 64, M / 64), 256, 0, stream>>>(
            H, wqkv_bf + (size_t)l * 196608, bqkv + (size_t)l * 768, QKVb, M, 768, D_);
        attn_mfma<<<dim3(T_ / 64, H_, B_), 256, 0, stream>>>(QKVb, ATTb);
        layer_tail<<<M / 16, 512, 0, stream>>>(
            ATTb, wo_bf + (size_t)l * 65536, bo + (size_t)l * D_,
            w1_bf + (size_t)l * 131072, b1 + (size_t)l * DFF_,
            w2_bf + (size_t)l * 131072, b2 + (size_t)l * D_, H,
            ln1w + (size_t)l * D_, ln1b + (size_t)l * D_,
            ln2w + (size_t)l * D_, ln2b + (size_t)l * D_);
    }

    // ---- post stage
    gemm_conv16<256, 1><<<dim3(D_ / 64, M / 16), 256, 0, stream>>>(
        H, cw_post0, post_b0, A1, D_, part2);
    ln2d_apply<<<dim3(D_ * T_ / 1024, B_), 256, 0, stream>>>(
        A1, post_lnw0, post_lnb0, part2, A0, D_ * T_, 256);
    gemm_conv16<256, 0><<<dim3(CIN_ / 64, M / 16), 256, 0, stream>>>(
        A0, cw_post1, post_b1, A1, CIN_, part2);
    ln2d_apply<<<dim3(CIN_ * T_ / 1024, B_), 256, 0, stream>>>(
        A1, post_lnw1, post_lnb1, part2, (float*)d_out, CIN_ * T_, 128);
}